// Round 5
// baseline (969.066 us; speedup 1.0000x reference)
//
#include <hip/hip_runtime.h>

// ---------------- constants ----------------
#define T_LEN 2048
#define DM    768
#define DI    1536
#define DS    16
#define BB    2
#define NROWS (BB * T_LEN)   // 4096
#define NCH   128            // scan chunks per sequence
#define CLEN  16             // chunk length  (1536 scan blocks = 6/CU)
#define NSEG  8              // segments
#define SEGC  16             // chunks per segment

// param-buffer (f32) segment offsets (elements)
#define OFF_DTB 0
#define OFF_A   6144
#define OFF_DP  104448
#define OFF_CW  110592
#define OFF_CB  135168
#define OFF_LG  141312
#define OFF_LB  144384
#define PRM_TOT 147456

typedef __attribute__((ext_vector_type(8))) short bh8;
typedef __attribute__((ext_vector_type(4))) float f32x4;

typedef const __attribute__((address_space(1))) void as1_void;
typedef __attribute__((address_space(3))) void as3_void;

__device__ __forceinline__ void glds16(const void* g, void* l) {
    __builtin_amdgcn_global_load_lds((as1_void*)g, (as3_void*)l, 16, 0, 0);
}

// ---------------- small helpers ----------------
__device__ __forceinline__ float bf2f(unsigned short u) {
    return __uint_as_float(((unsigned)u) << 16);
}
__device__ __forceinline__ unsigned short f2bf(float f) {
    unsigned u = __float_as_uint(f);
    u += 0x7FFFu + ((u >> 16) & 1u);   // RNE
    return (unsigned short)(u >> 16);
}

// load 8 consecutive elements as float (e0 multiple of 8)
__device__ __forceinline__ void ld8(const void* p, long e0, int bf, float* v) {
    if (bf) {
        bh8 u = *(const bh8*)((const unsigned short*)p + e0);
#pragma unroll
        for (int j = 0; j < 8; ++j) v[j] = bf2f((unsigned short)u[j]);
    } else {
        const f32x4* q = (const f32x4*)((const float*)p + e0);
        f32x4 a = q[0], b = q[1];
#pragma unroll
        for (int j = 0; j < 4; ++j) { v[j] = a[j]; v[4 + j] = b[j]; }
    }
}

// copy 8 elements to bf16 dst
__device__ __forceinline__ void cp8(unsigned short* dst, long de0,
                                    const void* src, long se0, int bf) {
    if (bf) {
        *(bh8*)&dst[de0] = *(const bh8*)((const unsigned short*)src + se0);
    } else {
        const f32x4* q = (const f32x4*)((const float*)src + se0);
        f32x4 a = q[0], b = q[1];
        bh8 o;
#pragma unroll
        for (int j = 0; j < 4; ++j) { o[j] = (short)f2bf(a[j]); o[4 + j] = (short)f2bf(b[j]); }
        *(bh8*)&dst[de0] = o;
    }
}

// ---------------- dtype sniffer ----------------
__global__ void k_sniff(const unsigned short* __restrict__ x, int* __restrict__ flag) {
    __shared__ int cnt[4];
    int tid = threadIdx.x;
    int local = 0;
#pragma unroll
    for (int j = 0; j < 4; ++j) {
        unsigned short u = x[tid * 4 + j];
        int e = (u >> 7) & 0xFF;
        if (e >= 100 && e <= 140) local++;
    }
    for (int off = 32; off; off >>= 1) local += __shfl_down(local, off, 64);
    if ((tid & 63) == 0) cnt[tid >> 6] = local;
    __syncthreads();
    if (tid == 0) {
        int tot = cnt[0] + cnt[1] + cnt[2] + cnt[3];
        *flag = (tot >= 900) ? 1 : 0;
    }
}

// ---------------- fused preamble conversion (8 elems / thread, 16B IO) ----------------
__global__ void k_prep(const void* in_x, const void* in_inw, const void* in_ow,
                       const void* in_xpw, const void* in_dtw,
                       const void* dtb, const void* alog, const void* dpar,
                       const void* cw, const void* cb, const void* lg, const void* lb,
                       unsigned short* __restrict__ xbf, float* __restrict__ xf,
                       unsigned short* __restrict__ Win, unsigned short* __restrict__ Wout,
                       unsigned short* __restrict__ Wxp, unsigned short* __restrict__ Wdt,
                       float* __restrict__ prm, const int* __restrict__ flag) {
    const long G0 = 393216L;            // x groups (3145728/8)
    const long G1 = G0 + 1179648L;      // in_proj_w
    const long G2 = G1 + 589824L;       // out_proj_w
    const long G3 = G2 + 98304L;        // x_proj_w padded
    const long G4 = G3 + 49152L;        // dt_proj_w padded
    const long G5 = G4 + 18432L;        // params
    int bf = *flag;
    long g = (long)blockIdx.x * 256 + threadIdx.x;
    if (g >= G5) return;
    if (g < G0) {
        long e0 = g * 8;
        float v[8];
        ld8(in_x, e0, bf, v);
        bh8 o;
#pragma unroll
        for (int j = 0; j < 8; ++j) o[j] = (short)f2bf(v[j]);
        *(bh8*)&xbf[e0] = o;
        f32x4 a, b;
#pragma unroll
        for (int j = 0; j < 4; ++j) { a[j] = v[j]; b[j] = v[4 + j]; }
        ((f32x4*)&xf[e0])[0] = a;
        ((f32x4*)&xf[e0])[1] = b;
    } else if (g < G1) {
        long e0 = (g - G0) * 8;
        cp8(Win, e0, in_inw, e0, bf);
    } else if (g < G2) {
        long e0 = (g - G1) * 8;
        cp8(Wout, e0, in_ow, e0, bf);
    } else if (g < G3) {
        long e0 = (g - G2) * 8;
        int c = (int)(e0 % 1536);
        long rl = e0 / 1536;
        int r = (int)(rl % 128);
        int l = (int)(rl / 128);
        if (r < 80) cp8(Wxp, e0, in_xpw, ((long)l * 80 + r) * 1536 + c, bf);
        else        *(bh8*)&Wxp[e0] = (bh8)(short)0;
    } else if (g < G4) {
        long e0 = (g - G3) * 8;
        int c = (int)(e0 & 63);
        long rl = e0 >> 6;
        int d = (int)(rl % 1536);
        int l = (int)(rl / 1536);
        if (c < 48) cp8(Wdt, e0, in_dtw, ((long)l * 1536 + d) * 48 + c, bf);
        else        *(bh8*)&Wdt[e0] = (bh8)(short)0;
    } else {
        long e0 = (g - G4) * 8;
        float v[8];
        if (e0 < OFF_A)        ld8(dtb,  e0 - OFF_DTB, bf, v);
        else if (e0 < OFF_DP) {
            ld8(alog, e0 - OFF_A, bf, v);
#pragma unroll
            for (int j = 0; j < 8; ++j) v[j] = -__expf(v[j]);
        }
        else if (e0 < OFF_CW)  ld8(dpar, e0 - OFF_DP, bf, v);
        else if (e0 < OFF_CB)  ld8(cw,   e0 - OFF_CW, bf, v);
        else if (e0 < OFF_LG)  ld8(cb,   e0 - OFF_CB, bf, v);
        else if (e0 < OFF_LB)  ld8(lg,   e0 - OFF_LG, bf, v);
        else                   ld8(lb,   e0 - OFF_LB, bf, v);
        f32x4 a, b;
#pragma unroll
        for (int j = 0; j < 4; ++j) { a[j] = v[j]; b[j] = v[4 + j]; }
        ((f32x4*)&prm[e0])[0] = a;
        ((f32x4*)&prm[e0])[1] = b;
    }
}

// ---------------- in_proj GEMM: 128x128 tile, bf16 in, bf16 out ----------------
__global__ __launch_bounds__(256) void k_gemm128(const unsigned short* __restrict__ A,
                                                 const unsigned short* __restrict__ B,
                                                 unsigned short* __restrict__ C,
                                                 int M, int N, int K) {
    __shared__ __align__(16) unsigned short As[128 * 32];
    __shared__ __align__(16) unsigned short Bs[128 * 32];
    const int tid = threadIdx.x;
    const int lane = tid & 63, wid = tid >> 6;
    const int wm = wid >> 1, wn = wid & 1;
    const long arow0 = (long)blockIdx.y * 128;
    const long bcol0 = (long)blockIdx.x * 128;
    const int r16 = lane >> 2;
    const int c8  = (lane & 3) * 8;
    f32x4 acc[4][4] = {};

    for (int k0 = 0; k0 < K; k0 += 32) {
#pragma unroll
        for (int j = 0; j < 2; ++j) {
            int chunk = wid + j * 4;
            int row = chunk * 16 + r16;
            glds16(&A[(arow0 + row) * K + k0 + c8], &As[chunk * 512]);
            glds16(&B[(bcol0 + row) * K + k0 + c8], &Bs[chunk * 512]);
        }
        __syncthreads();
        const int row = lane & 15, q8 = (lane >> 4) * 8;
        bh8 af[4], bfr[4];
#pragma unroll
        for (int i = 0; i < 4; ++i) af[i] = *(const bh8*)&As[(wm * 64 + i * 16 + row) * 32 + q8];
#pragma unroll
        for (int i = 0; i < 4; ++i) bfr[i] = *(const bh8*)&Bs[(wn * 64 + i * 16 + row) * 32 + q8];
#pragma unroll
        for (int i = 0; i < 4; ++i)
#pragma unroll
            for (int j = 0; j < 4; ++j)
                acc[i][j] = __builtin_amdgcn_mfma_f32_16x16x32_bf16(af[i], bfr[j], acc[i][j], 0, 0, 0);
        __syncthreads();
    }
    const int crow = (lane >> 4) * 4, ccol = lane & 15;
#pragma unroll
    for (int i = 0; i < 4; ++i)
#pragma unroll
        for (int j = 0; j < 4; ++j)
#pragma unroll
            for (int r = 0; r < 4; ++r) {
                long gr = arow0 + wm * 64 + i * 16 + crow + r;
                long gc = bcol0 + wn * 64 + j * 16 + ccol;
                C[gr * N + gc] = f2bf(acc[i][j][r]);
            }
}

// ---------------- x_proj GEMM with fused causal-conv+SiLU A-operand ----------------
// A(t,d) = silu(conv(xz_x)); B = Wxp [128,1536]; split-K=4, atomic f32 accum.
// grid (2, 64, 4): 64 t-rows x 64 e-cols, k-slice 384 d
__global__ __launch_bounds__(256) void k_xproj(const unsigned short* __restrict__ xz,
                                               const unsigned short* __restrict__ B,
                                               const float* __restrict__ cw,
                                               const float* __restrict__ cb,
                                               float* __restrict__ C) {
    __shared__ __align__(16) unsigned short As[64 * 32];
    __shared__ __align__(16) unsigned short Bs[64 * 32];
    const int tid = threadIdx.x;
    const int lane = tid & 63, w = tid >> 6;
    const int wm = w >> 1, wn = w & 1;
    const long arow0 = (long)blockIdx.y * 64;
    const long bcol0 = (long)blockIdx.x * 64;
    const int kbase = blockIdx.z * 384;
    const int r4 = lane >> 2;
    const int c8 = (lane & 3) * 8;
    const int t_o = tid >> 2;           // 0..63
    const int dl  = (tid & 3) * 8;      // 0,8,16,24
    const int sp  = (int)((arow0 + t_o) & (T_LEN - 1));  // in-sequence pos
    f32x4 acc[2][2] = {};

    for (int kk = 0; kk < 384; kk += 32) {
        const int k0 = kbase + kk;
        // B staging (async, drained by the syncthreads below)
        glds16(&B[(bcol0 + w * 16 + r4) * DI + k0 + c8], &Bs[w * 512]);
        // A: conv + silu for row (arow0+t_o), d-cols k0+dl .. +7
        const int dg = k0 + dl;
        float xv[4][8];
#pragma unroll
        for (int rr = 0; rr < 4; ++rr) {
            if (sp - 3 + rr >= 0) {
                bh8 u = *(const bh8*)&xz[(arow0 + t_o - 3 + rr) * 3072 + dg];
#pragma unroll
                for (int q = 0; q < 8; ++q) xv[rr][q] = bf2f((unsigned short)u[q]);
            } else {
#pragma unroll
                for (int q = 0; q < 8; ++q) xv[rr][q] = 0.f;
            }
        }
        bh8 o;
#pragma unroll
        for (int q = 0; q < 8; ++q) {
            const f32x4 w4 = *(const f32x4*)&cw[(dg + q) * 4];
            float a = cb[dg + q] + w4[0] * xv[0][q] + w4[1] * xv[1][q]
                                 + w4[2] * xv[2][q] + w4[3] * xv[3][q];
            a = a / (1.f + __expf(-a));
            o[q] = (short)f2bf(a);
        }
        *(bh8*)&As[t_o * 32 + dl] = o;
        __syncthreads();
        const int row2 = lane & 15, q8 = (lane >> 4) * 8;
        bh8 af[2], bfr[2];
#pragma unroll
        for (int i = 0; i < 2; ++i) af[i] = *(const bh8*)&As[(wm * 32 + i * 16 + row2) * 32 + q8];
#pragma unroll
        for (int i = 0; i < 2; ++i) bfr[i] = *(const bh8*)&Bs[(wn * 32 + i * 16 + row2) * 32 + q8];
#pragma unroll
        for (int i = 0; i < 2; ++i)
#pragma unroll
            for (int j = 0; j < 2; ++j)
                acc[i][j] = __builtin_amdgcn_mfma_f32_16x16x32_bf16(af[i], bfr[j], acc[i][j], 0, 0, 0);
        __syncthreads();
    }
    const int crow = (lane >> 4) * 4, ccol = lane & 15;
#pragma unroll
    for (int i = 0; i < 2; ++i)
#pragma unroll
        for (int j = 0; j < 2; ++j)
#pragma unroll
            for (int r = 0; r < 4; ++r) {
                long gr = arow0 + wm * 32 + i * 16 + crow + r;
                long gc = bcol0 + wn * 32 + j * 16 + ccol;
                atomicAdd(&C[gr * 128 + gc], acc[i][j][r]);
            }
}

// ---------------- dt_proj fused: Dbl f32 -> lowrank bf16 (pad) @ Wdt^T + bias -> softplus -> bf16 ----------------
__global__ __launch_bounds__(256) void k_dtproj(const float* __restrict__ Dbl,
                                                const unsigned short* __restrict__ Wdt,
                                                const float* __restrict__ bias,
                                                unsigned short* __restrict__ Dt) {
    __shared__ __align__(16) unsigned short As[2 * 64 * 32];
    __shared__ __align__(16) unsigned short Bs[2 * 64 * 32];
    const int tid = threadIdx.x;
    const int lane = tid & 63, wid = tid >> 6;
    const int wm = wid >> 1, wn = wid & 1;
    const long arow0 = (long)blockIdx.y * 64;
    const long bcol0 = (long)blockIdx.x * 64;

    {
        int r = tid >> 2;
        int cs = (tid & 3) * 16;
        unsigned short tmp[16];
#pragma unroll
        for (int q = 0; q < 4; ++q) {
            int col0 = cs + q * 4;
            if (col0 < 48) {
                f32x4 v = *(const f32x4*)&Dbl[(arow0 + r) * 128 + col0];
#pragma unroll
                for (int j = 0; j < 4; ++j) tmp[q * 4 + j] = f2bf(v[j]);
            } else {
#pragma unroll
                for (int j = 0; j < 4; ++j) tmp[q * 4 + j] = 0;
            }
        }
        int p = cs >> 5;
        int cp = cs & 31;
        *(bh8*)&As[p * 2048 + r * 32 + cp]     = *(bh8*)&tmp[0];
        *(bh8*)&As[p * 2048 + r * 32 + cp + 8] = *(bh8*)&tmp[8];
    }
#pragma unroll
    for (int j = 0; j < 2; ++j) {
        int chunk = tid + j * 256;
        int p = chunk >> 8;
        int rem = chunk & 255;
        int row = rem >> 2;
        int c4 = rem & 3;
        glds16(&Wdt[(bcol0 + row) * 64 + p * 32 + c4 * 8], &Bs[chunk * 8]);
    }
    __syncthreads();

    const int row2 = lane & 15, q8 = (lane >> 4) * 8;
    f32x4 acc[2][2] = {};
#pragma unroll
    for (int p = 0; p < 2; ++p) {
        bh8 af[2], bfr[2];
#pragma unroll
        for (int i = 0; i < 2; ++i) af[i] = *(const bh8*)&As[p * 2048 + (wm * 32 + i * 16 + row2) * 32 + q8];
#pragma unroll
        for (int i = 0; i < 2; ++i) bfr[i] = *(const bh8*)&Bs[p * 2048 + (wn * 32 + i * 16 + row2) * 32 + q8];
#pragma unroll
        for (int i = 0; i < 2; ++i)
#pragma unroll
            for (int j = 0; j < 2; ++j)
                acc[i][j] = __builtin_amdgcn_mfma_f32_16x16x32_bf16(af[i], bfr[j], acc[i][j], 0, 0, 0);
    }
    const int crow = (lane >> 4) * 4, ccol = lane & 15;
#pragma unroll
    for (int i = 0; i < 2; ++i)
#pragma unroll
        for (int j = 0; j < 2; ++j)
#pragma unroll
            for (int r = 0; r < 4; ++r) {
                long gr = arow0 + wm * 32 + i * 16 + crow + r;
                long gc = bcol0 + wn * 32 + j * 16 + ccol;
                float v = acc[i][j][r] + bias[gc];
                v = (v > 20.f) ? v : log1pf(__expf(v));
                Dt[gr * DI + gc] = f2bf(v);
            }
}

// ---------------- out_proj GEMM: 64x64 tile, bf16 in, f32 out; grid (12,64) ----------------
__global__ __launch_bounds__(256) void k_outproj(const unsigned short* __restrict__ A,
                                                 const unsigned short* __restrict__ B,
                                                 float* __restrict__ C) {
    __shared__ __align__(16) unsigned short As[64 * 32];
    __shared__ __align__(16) unsigned short Bs[64 * 32];
    const int tid = threadIdx.x;
    const int lane = tid & 63, wid = tid >> 6;
    const int wm = wid >> 1, wn = wid & 1;
    const long arow0 = (long)blockIdx.y * 64;
    const long bcol0 = (long)blockIdx.x * 64;
    const int r16 = lane >> 2;
    const int c8  = (lane & 3) * 8;
    f32x4 acc[2][2] = {};

    for (int k0 = 0; k0 < DI; k0 += 32) {
        int row = wid * 16 + r16;
        glds16(&A[(arow0 + row) * DI + k0 + c8], &As[wid * 512]);
        glds16(&B[(bcol0 + row) * DI + k0 + c8], &Bs[wid * 512]);
        __syncthreads();
        const int row2 = lane & 15, q8 = (lane >> 4) * 8;
        bh8 af[2], bfr[2];
#pragma unroll
        for (int i = 0; i < 2; ++i) af[i] = *(const bh8*)&As[(wm * 32 + i * 16 + row2) * 32 + q8];
#pragma unroll
        for (int i = 0; i < 2; ++i) bfr[i] = *(const bh8*)&Bs[(wn * 32 + i * 16 + row2) * 32 + q8];
#pragma unroll
        for (int i = 0; i < 2; ++i)
#pragma unroll
            for (int j = 0; j < 2; ++j)
                acc[i][j] = __builtin_amdgcn_mfma_f32_16x16x32_bf16(af[i], bfr[j], acc[i][j], 0, 0, 0);
        __syncthreads();
    }
    const int crow = (lane >> 4) * 4, ccol = lane & 15;
#pragma unroll
    for (int i = 0; i < 2; ++i)
#pragma unroll
        for (int j = 0; j < 2; ++j)
#pragma unroll
            for (int r = 0; r < 4; ++r) {
                long gr = arow0 + wm * 32 + i * 16 + crow + r;
                long gc = bcol0 + wn * 32 + j * 16 + ccol;
                C[gr * DM + gc] = acc[i][j][r];
            }
}

// ---------------- chunked selective scan (conv fused on the fly) ----------------
// phase 1: per (b,chunk,d): local scan from h=0; store final h and sum(dt)
__global__ __launch_bounds__(256) void k_scan1(const unsigned short* __restrict__ dt,
                                               const unsigned short* __restrict__ xz,
                                               const float* __restrict__ dbl,
                                               const float* __restrict__ An,
                                               const float* __restrict__ cw,
                                               const float* __restrict__ cb,
                                               float* __restrict__ hch,
                                               float* __restrict__ sdtb) {
    const int tid = threadIdx.x;
    const int db = blockIdx.x % 6;
    const int c  = (blockIdx.x / 6) % NCH;
    const int b  = blockIdx.x / (6 * NCH);
    const int d  = db * 256 + tid;
    const int t0 = c * CLEN;
    float h[DS], An_r[DS];
    const f32x4* Ap = (const f32x4*)(An + (long)d * DS);
#pragma unroll
    for (int q = 0; q < 4; ++q) {
        f32x4 a4 = Ap[q];
#pragma unroll
        for (int j = 0; j < 4; ++j) { An_r[q * 4 + j] = a4[j]; h[q * 4 + j] = 0.f; }
    }
    const f32x4 w4 = *(const f32x4*)&cw[d * 4];
    const float cbv = cb[d];
    const long rowb = (long)b * T_LEN + t0;
    float x1, x2, x3;
    if (c == 0) { x1 = x2 = x3 = 0.f; }
    else {
        x1 = bf2f(xz[(rowb - 1) * 3072 + d]);
        x2 = bf2f(xz[(rowb - 2) * 3072 + d]);
        x3 = bf2f(xz[(rowb - 3) * 3072 + d]);
    }
    float sdt = 0.f;
#pragma unroll 4
    for (int s = 0; s < CLEN; ++s) {
        long bt = rowb + s;
        float xt = bf2f(xz[bt * 3072 + d]);
        float a = cbv + w4[0] * x3 + w4[1] * x2 + w4[2] * x1 + w4[3] * xt;
        float xcv = a / (1.f + __expf(-a));
        x3 = x2; x2 = x1; x1 = xt;
        float dtv = bf2f(dt[bt * DI + d]);
        int bi = __builtin_amdgcn_readfirstlane((int)(bt * 128 + 48));
        const f32x4* bp = (const f32x4*)(dbl + bi);
        float Bv[DS];
#pragma unroll
        for (int q = 0; q < 4; ++q) {
            f32x4 b4 = bp[q];
#pragma unroll
            for (int j = 0; j < 4; ++j) Bv[q * 4 + j] = b4[j];
        }
        float du = dtv * xcv;
        sdt += dtv;
#pragma unroll
        for (int n = 0; n < DS; ++n)
            h[n] = __expf(An_r[n] * dtv) * h[n] + du * Bv[n];
    }
    long o = (((long)b * NCH + c) * DI + d) * DS;
    f32x4* hp = (f32x4*)(hch + o);
#pragma unroll
    for (int q = 0; q < 4; ++q) {
        f32x4 h4;
#pragma unroll
        for (int j = 0; j < 4; ++j) h4[j] = h[q * 4 + j];
        hp[q] = h4;
    }
    sdtb[((long)b * NCH + c) * DI + d] = sdt;
}

// phase 2a: within-segment combine over SEGC chunks; write prefix-in-place + seg aggregates
__global__ __launch_bounds__(256) void k_scan2a(float* __restrict__ hbuf,
                                                const float* __restrict__ sdtb,
                                                const float* __restrict__ An,
                                                float* __restrict__ cum,
                                                float* __restrict__ Gseg,
                                                float* __restrict__ Sseg) {
    long gid = (long)blockIdx.x * 256 + threadIdx.x;
    int n = (int)(gid & 15);
    long t = gid >> 4;
    int d  = (int)(t % DI);
    int sg = (int)((t / DI) & (NSEG - 1));
    int b  = (int)(t / (DI * NSEG));
    float an = An[(long)d * DS + n];
    float h = 0.f, cs = 0.f;
    for (int i = 0; i < SEGC; ++i) {
        int c = sg * SEGC + i;
        long rowi = ((long)b * NCH + c) * DI + d;
        long idx = rowi * DS + n;
        float sdt = sdtb[rowi];
        float g = hbuf[idx];
        hbuf[idx] = h;
        if (n == 0) cum[rowi] = cs;
        h = __expf(an * sdt) * h + g;
        cs += sdt;
    }
    long gi = (((long)b * NSEG + sg) * DI + d) * DS + n;
    Gseg[gi] = h;
    if (n == 0) Sseg[((long)b * NSEG + sg) * DI + d] = cs;
}

// phase 3: combine <=7 segment aggregates inline (scan2b folded); rescan with conv
// fused; fuse y=(scan + xc*D)*silu(z); emit bf16
__global__ __launch_bounds__(256) void k_scan3(const unsigned short* __restrict__ dt,
                                               const unsigned short* __restrict__ xz,
                                               const float* __restrict__ dbl,
                                               const float* __restrict__ An,
                                               const float* __restrict__ cw,
                                               const float* __restrict__ cb,
                                               const float* __restrict__ Dp,
                                               const float* __restrict__ hpref,
                                               const float* __restrict__ cum,
                                               const float* __restrict__ Gseg,
                                               const float* __restrict__ Sseg,
                                               unsigned short* __restrict__ ybf) {
    const int tid = threadIdx.x;
    const int db = blockIdx.x % 6;
    const int c  = (blockIdx.x / 6) % NCH;
    const int b  = blockIdx.x / (6 * NCH);
    const int d  = db * 256 + tid;
    const int t0 = c * CLEN;
    const int sg = c / SEGC;
    float h[DS], An_r[DS];
    long rowi = ((long)b * NCH + c) * DI + d;
    long o = rowi * DS;
    const float cs = cum[rowi];
    const f32x4* Ap = (const f32x4*)(An + (long)d * DS);
#pragma unroll
    for (int q = 0; q < 4; ++q) {
        f32x4 a4 = Ap[q];
#pragma unroll
        for (int j = 0; j < 4; ++j) An_r[q * 4 + j] = a4[j];
    }
    // fold of scan2b: combine segments 0..sg-1
    float Hn[DS];
#pragma unroll
    for (int n = 0; n < DS; ++n) Hn[n] = 0.f;
    for (int s2 = 0; s2 < sg; ++s2) {
        long gi = (((long)b * NSEG + s2) * DI + d) * DS;
        float S = Sseg[((long)b * NSEG + s2) * DI + d];
        const f32x4* Gp = (const f32x4*)(Gseg + gi);
#pragma unroll
        for (int q = 0; q < 4; ++q) {
            f32x4 g4 = Gp[q];
#pragma unroll
            for (int j = 0; j < 4; ++j) {
                int n = q * 4 + j;
                Hn[n] = __expf(An_r[n] * S) * Hn[n] + g4[j];
            }
        }
    }
    const f32x4* Pp = (const f32x4*)(hpref + o);
#pragma unroll
    for (int q = 0; q < 4; ++q) {
        f32x4 p4 = Pp[q];
#pragma unroll
        for (int j = 0; j < 4; ++j) {
            int n = q * 4 + j;
            h[n] = __expf(An_r[n] * cs) * Hn[n] + p4[j];
        }
    }
    const float dcoef = Dp[d];
    const f32x4 w4 = *(const f32x4*)&cw[d * 4];
    const float cbv = cb[d];
    const long rowb = (long)b * T_LEN + t0;
    float x1, x2, x3;
    if (c == 0) { x1 = x2 = x3 = 0.f; }
    else {
        x1 = bf2f(xz[(rowb - 1) * 3072 + d]);
        x2 = bf2f(xz[(rowb - 2) * 3072 + d]);
        x3 = bf2f(xz[(rowb - 3) * 3072 + d]);
    }
#pragma unroll 4
    for (int s = 0; s < CLEN; ++s) {
        long bt = rowb + s;
        float xt = bf2f(xz[bt * 3072 + d]);
        float a = cbv + w4[0] * x3 + w4[1] * x2 + w4[2] * x1 + w4[3] * xt;
        float xcv = a / (1.f + __expf(-a));
        x3 = x2; x2 = x1; x1 = xt;
        float dtv = bf2f(dt[bt * DI + d]);
        int bi = __builtin_amdgcn_readfirstlane((int)(bt * 128 + 48));
        const f32x4* bp = (const f32x4*)(dbl + bi);
        float Bv[DS], Cv[DS];
#pragma unroll
        for (int q = 0; q < 4; ++q) {
            f32x4 b4 = bp[q], c4 = bp[q + 4];
#pragma unroll
            for (int j = 0; j < 4; ++j) { Bv[q * 4 + j] = b4[j]; Cv[q * 4 + j] = c4[j]; }
        }
        float du = dtv * xcv;
        float yp[4] = {xcv * dcoef, 0.f, 0.f, 0.f};
#pragma unroll
        for (int n = 0; n < DS; ++n) {
            h[n] = __expf(An_r[n] * dtv) * h[n] + du * Bv[n];
            yp[n & 3] += h[n] * Cv[n];
        }
        float y = (yp[0] + yp[1]) + (yp[2] + yp[3]);
        float zv = bf2f(xz[bt * 3072 + DI + d]);
        y *= zv / (1.f + __expf(-zv));
        ybf[bt * DI + d] = f2bf(y);
    }
}

// ---------------- LayerNorm + residual (+ final output store) ----------------
__global__ __launch_bounds__(256) void k_ln(const float* __restrict__ prj,
                                            float* __restrict__ x,
                                            unsigned short* __restrict__ xbf,
                                            const float* __restrict__ lg,
                                            const float* __restrict__ lb,
                                            void* __restrict__ dout,
                                            int is_last, const int* __restrict__ flag) {
    __shared__ float red[8];
    const int row = blockIdx.x;
    const int tid = threadIdx.x;
    float v[3];
    float s = 0.f, s2 = 0.f;
#pragma unroll
    for (int j = 0; j < 3; ++j) {
        v[j] = prj[(long)row * DM + tid + j * 256];
        s += v[j];
        s2 += v[j] * v[j];
    }
    for (int off = 32; off; off >>= 1) {
        s  += __shfl_down(s, off, 64);
        s2 += __shfl_down(s2, off, 64);
    }
    if ((tid & 63) == 0) { red[tid >> 6] = s; red[4 + (tid >> 6)] = s2; }
    __syncthreads();
    float S  = red[0] + red[1] + red[2] + red[3];
    float S2 = red[4] + red[5] + red[6] + red[7];
    float mu = S * (1.f / DM);
    float var = S2 * (1.f / DM) - mu * mu;
    float rs = rsqrtf(var + 1e-5f);
    int bf = *flag;
#pragma unroll
    for (int j = 0; j < 3; ++j) {
        int e = tid + j * 256;
        long idx = (long)row * DM + e;
        float out = (v[j] - mu) * rs * lg[e] + lb[e] + x[idx];
        x[idx] = out;
        xbf[idx] = f2bf(out);
        if (is_last) {
            if (bf) ((unsigned short*)dout)[idx] = f2bf(out);
            else    ((float*)dout)[idx] = out;
        }
    }
}

// ---------------- host launcher ----------------
extern "C" void kernel_launch(void* const* d_in, const int* in_sizes, int n_in,
                              void* d_out, int out_size, void* d_ws, size_t ws_size,
                              hipStream_t stream) {
    char* ws = (char*)d_ws;
    const size_t O_FLAG = 0;
    const size_t O_WIN  = 256;
    const size_t O_WXP  = O_WIN  + 18874368;
    const size_t O_WDT  = O_WXP  + 1572864;
    const size_t O_WOUT = O_WDT  + 786432;
    const size_t O_PRM  = O_WOUT + 9437184;
    const size_t O_XBF  = O_PRM  + 589824;
    const size_t O_XF   = O_XBF  + 6291456;
    const size_t O_XZ   = O_XF   + 12582912;   // bf16 [4096,3072]; f32 Prj aliases
    const size_t O_DBL  = O_XZ   + 25165824;   // f32 [4096,128]
    const size_t O_DT   = O_DBL  + 2097152;    // bf16 [4096,1536]
    const size_t O_HCH  = O_DT   + 12582912;   // f32 [2,128,1536,16]
    const size_t O_SDT  = O_HCH  + 25165824;
    const size_t O_CUM  = O_SDT  + 1572864;
    const size_t O_GSEG = O_CUM  + 1572864;
    const size_t O_SSEG = O_GSEG + 1572864;
    const size_t O_YBF  = O_SSEG + 98304;

    int* flag = (int*)(ws + O_FLAG);
    unsigned short* Win  = (unsigned short*)(ws + O_WIN);
    unsigned short* Wxp  = (unsigned short*)(ws + O_WXP);
    unsigned short* Wdt  = (unsigned short*)(ws + O_WDT);
    unsigned short* Wout = (unsigned short*)(ws + O_WOUT);
    float* prm = (float*)(ws + O_PRM);
    unsigned short* Xbf = (unsigned short*)(ws + O_XBF);
    float* Xf  = (float*)(ws + O_XF);
    unsigned short* Xz = (unsigned short*)(ws + O_XZ);
    float* Dbl = (float*)(ws + O_DBL);
    unsigned short* Dt = (unsigned short*)(ws + O_DT);
    float* Hch = (float*)(ws + O_HCH);
    float* Sdt = (float*)(ws + O_SDT);
    float* Cum = (float*)(ws + O_CUM);
    float* Gsg = (float*)(ws + O_GSEG);
    float* Ssg = (float*)(ws + O_SSEG);
    unsigned short* Ybf = (unsigned short*)(ws + O_YBF);
    float* Prj = (float*)(ws + O_XZ);   // alias: z consumed by scan3 before out_proj writes

    k_sniff<<<1, 256, 0, stream>>>((const unsigned short*)d_in[0], flag);
    k_prep<<<9096, 256, 0, stream>>>(d_in[0], d_in[1], d_in[9], d_in[4], d_in[5],
                                     d_in[6], d_in[7], d_in[8], d_in[2], d_in[3],
                                     d_in[10], d_in[11],
                                     Xbf, Xf, Win, Wout, Wxp, Wdt, prm, flag);

    for (int l = 0; l < 4; ++l) {
        const unsigned short* winL  = Win  + (size_t)l * 3072 * 768;
        const unsigned short* wxpL  = Wxp  + (size_t)l * 128 * 1536;
        const unsigned short* wdtL  = Wdt  + (size_t)l * 1536 * 64;
        const unsigned short* woutL = Wout + (size_t)l * 768 * 1536;
        const float* cwL  = prm + OFF_CW  + (size_t)l * DI * 4;
        const float* cbL  = prm + OFF_CB  + (size_t)l * DI;
        const float* dtbL = prm + OFF_DTB + (size_t)l * DI;
        const float* anL  = prm + OFF_A   + (size_t)l * DI * DS;
        const float* dpL  = prm + OFF_DP  + (size_t)l * DI;
        const float* lgL  = prm + OFF_LG  + (size_t)l * DM;
        const float* lbL  = prm + OFF_LB  + (size_t)l * DM;

        k_gemm128<<<dim3(24, 32), 256, 0, stream>>>(Xbf, winL, Xz, NROWS, 2 * DI, DM);
        hipMemsetAsync(Dbl, 0, 2097152, stream);
        k_xproj<<<dim3(2, 64, 4), 256, 0, stream>>>(Xz, wxpL, cwL, cbL, Dbl);
        k_dtproj<<<dim3(24, 64), 256, 0, stream>>>(Dbl, wdtL, dtbL, Dt);
        k_scan1<<<BB * NCH * 6, 256, 0, stream>>>(Dt, Xz, Dbl, anL, cwL, cbL, Hch, Sdt);
        k_scan2a<<<1536, 256, 0, stream>>>(Hch, Sdt, anL, Cum, Gsg, Ssg);
        k_scan3<<<BB * NCH * 6, 256, 0, stream>>>(Dt, Xz, Dbl, anL, cwL, cbL, dpL,
                                                  Hch, Cum, Gsg, Ssg, Ybf);
        k_outproj<<<dim3(12, 64), 256, 0, stream>>>(Ybf, woutL, Prj);
        k_ln<<<4096, 256, 0, stream>>>(Prj, Xf, Xbf, lgL, lbL, d_out, (l == 3) ? 1 : 0, flag);
    }
}

// Round 6
// 935.125 us; speedup vs baseline: 1.0363x; 1.0363x over previous
//
#include <hip/hip_runtime.h>

// ---------------- constants ----------------
#define T_LEN 2048
#define DM    768
#define DI    1536
#define DS    16
#define BB    2
#define NROWS (BB * T_LEN)   // 4096
#define NCH   64             // scan chunks per sequence
#define CLEN  32             // chunk length (768 scan blocks = 3/CU)
#define NSEG  8              // segments
#define SEGC  8              // chunks per segment

// param-buffer (f32) segment offsets (elements)
#define OFF_DTB 0
#define OFF_A   6144
#define OFF_DP  104448
#define OFF_CW  110592
#define OFF_CB  135168
#define OFF_LG  141312
#define OFF_LB  144384
#define PRM_TOT 147456

typedef __attribute__((ext_vector_type(8))) short bh8;
typedef __attribute__((ext_vector_type(4))) float f32x4;

typedef const __attribute__((address_space(1))) void as1_void;
typedef __attribute__((address_space(3))) void as3_void;

__device__ __forceinline__ void glds16(const void* g, void* l) {
    __builtin_amdgcn_global_load_lds((as1_void*)g, (as3_void*)l, 16, 0, 0);
}

// ---------------- small helpers ----------------
__device__ __forceinline__ float bf2f(unsigned short u) {
    return __uint_as_float(((unsigned)u) << 16);
}
__device__ __forceinline__ unsigned short f2bf(float f) {
    unsigned u = __float_as_uint(f);
    u += 0x7FFFu + ((u >> 16) & 1u);   // RNE
    return (unsigned short)(u >> 16);
}

__device__ __forceinline__ void ld8(const void* p, long e0, int bf, float* v) {
    if (bf) {
        bh8 u = *(const bh8*)((const unsigned short*)p + e0);
#pragma unroll
        for (int j = 0; j < 8; ++j) v[j] = bf2f((unsigned short)u[j]);
    } else {
        const f32x4* q = (const f32x4*)((const float*)p + e0);
        f32x4 a = q[0], b = q[1];
#pragma unroll
        for (int j = 0; j < 4; ++j) { v[j] = a[j]; v[4 + j] = b[j]; }
    }
}

__device__ __forceinline__ void cp8(unsigned short* dst, long de0,
                                    const void* src, long se0, int bf) {
    if (bf) {
        *(bh8*)&dst[de0] = *(const bh8*)((const unsigned short*)src + se0);
    } else {
        const f32x4* q = (const f32x4*)((const float*)src + se0);
        f32x4 a = q[0], b = q[1];
        bh8 o;
#pragma unroll
        for (int j = 0; j < 4; ++j) { o[j] = (short)f2bf(a[j]); o[4 + j] = (short)f2bf(b[j]); }
        *(bh8*)&dst[de0] = o;
    }
}

// ---------------- dtype sniffer ----------------
__global__ void k_sniff(const unsigned short* __restrict__ x, int* __restrict__ flag) {
    __shared__ int cnt[4];
    int tid = threadIdx.x;
    int local = 0;
#pragma unroll
    for (int j = 0; j < 4; ++j) {
        unsigned short u = x[tid * 4 + j];
        int e = (u >> 7) & 0xFF;
        if (e >= 100 && e <= 140) local++;
    }
    for (int off = 32; off; off >>= 1) local += __shfl_down(local, off, 64);
    if ((tid & 63) == 0) cnt[tid >> 6] = local;
    __syncthreads();
    if (tid == 0) {
        int tot = cnt[0] + cnt[1] + cnt[2] + cnt[3];
        *flag = (tot >= 900) ? 1 : 0;
    }
}

// ---------------- fused preamble conversion (8 elems / thread, 16B IO) ----------------
// extra tail range zeroes Dbl (split-K accumulator) for layer 0
__global__ void k_prep(const void* in_x, const void* in_inw, const void* in_ow,
                       const void* in_xpw, const void* in_dtw,
                       const void* dtb, const void* alog, const void* dpar,
                       const void* cw, const void* cb, const void* lg, const void* lb,
                       unsigned short* __restrict__ xbf, float* __restrict__ xf,
                       unsigned short* __restrict__ Win, unsigned short* __restrict__ Wout,
                       unsigned short* __restrict__ Wxp, unsigned short* __restrict__ Wdt,
                       float* __restrict__ prm, float* __restrict__ dblz,
                       const int* __restrict__ flag) {
    const long G0 = 393216L;            // x groups (3145728/8)
    const long G1 = G0 + 1179648L;      // in_proj_w
    const long G2 = G1 + 589824L;       // out_proj_w
    const long G3 = G2 + 98304L;        // x_proj_w padded
    const long G4 = G3 + 49152L;        // dt_proj_w padded
    const long G5 = G4 + 18432L;        // params
    const long G6 = G5 + 65536L;        // Dbl zero (524288 f32)
    int bf = *flag;
    long g = (long)blockIdx.x * 256 + threadIdx.x;
    if (g >= G6) return;
    if (g < G0) {
        long e0 = g * 8;
        float v[8];
        ld8(in_x, e0, bf, v);
        bh8 o;
#pragma unroll
        for (int j = 0; j < 8; ++j) o[j] = (short)f2bf(v[j]);
        *(bh8*)&xbf[e0] = o;
        f32x4 a, b;
#pragma unroll
        for (int j = 0; j < 4; ++j) { a[j] = v[j]; b[j] = v[4 + j]; }
        ((f32x4*)&xf[e0])[0] = a;
        ((f32x4*)&xf[e0])[1] = b;
    } else if (g < G1) {
        long e0 = (g - G0) * 8;
        cp8(Win, e0, in_inw, e0, bf);
    } else if (g < G2) {
        long e0 = (g - G1) * 8;
        cp8(Wout, e0, in_ow, e0, bf);
    } else if (g < G3) {
        long e0 = (g - G2) * 8;
        int c = (int)(e0 % 1536);
        long rl = e0 / 1536;
        int r = (int)(rl % 128);
        int l = (int)(rl / 128);
        if (r < 80) cp8(Wxp, e0, in_xpw, ((long)l * 80 + r) * 1536 + c, bf);
        else        *(bh8*)&Wxp[e0] = (bh8)(short)0;
    } else if (g < G4) {
        long e0 = (g - G3) * 8;
        int c = (int)(e0 & 63);
        long rl = e0 >> 6;
        int d = (int)(rl % 1536);
        int l = (int)(rl / 1536);
        if (c < 48) cp8(Wdt, e0, in_dtw, ((long)l * 1536 + d) * 48 + c, bf);
        else        *(bh8*)&Wdt[e0] = (bh8)(short)0;
    } else if (g < G5) {
        long e0 = (g - G4) * 8;
        float v[8];
        if (e0 < OFF_A)        ld8(dtb,  e0 - OFF_DTB, bf, v);
        else if (e0 < OFF_DP) {
            ld8(alog, e0 - OFF_A, bf, v);
#pragma unroll
            for (int j = 0; j < 8; ++j) v[j] = -__expf(v[j]);
        }
        else if (e0 < OFF_CW)  ld8(dpar, e0 - OFF_DP, bf, v);
        else if (e0 < OFF_CB)  ld8(cw,   e0 - OFF_CW, bf, v);
        else if (e0 < OFF_LG)  ld8(cb,   e0 - OFF_CB, bf, v);
        else if (e0 < OFF_LB)  ld8(lg,   e0 - OFF_LG, bf, v);
        else                   ld8(lb,   e0 - OFF_LB, bf, v);
        f32x4 a, b;
#pragma unroll
        for (int j = 0; j < 4; ++j) { a[j] = v[j]; b[j] = v[4 + j]; }
        ((f32x4*)&prm[e0])[0] = a;
        ((f32x4*)&prm[e0])[1] = b;
    } else {
        long e0 = (g - G5) * 8;
        f32x4 z = {0.f, 0.f, 0.f, 0.f};
        ((f32x4*)&dblz[e0])[0] = z;
        ((f32x4*)&dblz[e0])[1] = z;
    }
}

// ---------------- in_proj GEMM: 128x128 tile, XCD-swizzled, bf16 in, bf16 out ----------------
// grid (24, 32). Per-XCD region 12 cols x 8 rows -> 3.9 MB working set per 4 MB L2.
__global__ __launch_bounds__(256) void k_gemm128(const unsigned short* __restrict__ A,
                                                 const unsigned short* __restrict__ B,
                                                 unsigned short* __restrict__ C,
                                                 int M, int N, int K) {
    __shared__ __align__(16) unsigned short As[128 * 32];
    __shared__ __align__(16) unsigned short Bs[128 * 32];
    const int tid = threadIdx.x;
    const int lane = tid & 63, wid = tid >> 6;
    const int wm = wid >> 1, wn = wid & 1;
    const int id = blockIdx.y * 24 + blockIdx.x;
    const int xcd = id & 7, loc = id >> 3;
    const int bx = (xcd & 1) * 12 + loc % 12;
    const int by = (xcd >> 1) * 8 + loc / 12;
    const long arow0 = (long)by * 128;
    const long bcol0 = (long)bx * 128;
    const int r16 = lane >> 2;
    const int c8  = (lane & 3) * 8;
    f32x4 acc[4][4] = {};

    for (int k0 = 0; k0 < K; k0 += 32) {
#pragma unroll
        for (int j = 0; j < 2; ++j) {
            int chunk = wid + j * 4;
            int row = chunk * 16 + r16;
            glds16(&A[(arow0 + row) * K + k0 + c8], &As[chunk * 512]);
            glds16(&B[(bcol0 + row) * K + k0 + c8], &Bs[chunk * 512]);
        }
        __syncthreads();
        const int row = lane & 15, q8 = (lane >> 4) * 8;
        bh8 af[4], bfr[4];
#pragma unroll
        for (int i = 0; i < 4; ++i) af[i] = *(const bh8*)&As[(wm * 64 + i * 16 + row) * 32 + q8];
#pragma unroll
        for (int i = 0; i < 4; ++i) bfr[i] = *(const bh8*)&Bs[(wn * 64 + i * 16 + row) * 32 + q8];
#pragma unroll
        for (int i = 0; i < 4; ++i)
#pragma unroll
            for (int j = 0; j < 4; ++j)
                acc[i][j] = __builtin_amdgcn_mfma_f32_16x16x32_bf16(af[i], bfr[j], acc[i][j], 0, 0, 0);
        __syncthreads();
    }
    const int crow = (lane >> 4) * 4, ccol = lane & 15;
#pragma unroll
    for (int i = 0; i < 4; ++i)
#pragma unroll
        for (int j = 0; j < 4; ++j)
#pragma unroll
            for (int r = 0; r < 4; ++r) {
                long gr = arow0 + wm * 64 + i * 16 + crow + r;
                long gc = bcol0 + wn * 64 + j * 16 + ccol;
                C[gr * N + gc] = f2bf(acc[i][j][r]);
            }
}

// ---------------- x_proj GEMM with fused causal-conv+SiLU A-operand ----------------
// split-K=4, atomic f32 accum; grid (2, 64, 4)
__global__ __launch_bounds__(256) void k_xproj(const unsigned short* __restrict__ xz,
                                               const unsigned short* __restrict__ B,
                                               const float* __restrict__ cw,
                                               const float* __restrict__ cb,
                                               float* __restrict__ C) {
    __shared__ __align__(16) unsigned short As[64 * 32];
    __shared__ __align__(16) unsigned short Bs[64 * 32];
    const int tid = threadIdx.x;
    const int lane = tid & 63, w = tid >> 6;
    const int wm = w >> 1, wn = w & 1;
    const long arow0 = (long)blockIdx.y * 64;
    const long bcol0 = (long)blockIdx.x * 64;
    const int kbase = blockIdx.z * 384;
    const int r4 = lane >> 2;
    const int c8 = (lane & 3) * 8;
    const int t_o = tid >> 2;
    const int dl  = (tid & 3) * 8;
    const int sp  = (int)((arow0 + t_o) & (T_LEN - 1));
    f32x4 acc[2][2] = {};

    for (int kk = 0; kk < 384; kk += 32) {
        const int k0 = kbase + kk;
        glds16(&B[(bcol0 + w * 16 + r4) * DI + k0 + c8], &Bs[w * 512]);
        const int dg = k0 + dl;
        float xv[4][8];
#pragma unroll
        for (int rr = 0; rr < 4; ++rr) {
            if (sp - 3 + rr >= 0) {
                bh8 u = *(const bh8*)&xz[(arow0 + t_o - 3 + rr) * 3072 + dg];
#pragma unroll
                for (int q = 0; q < 8; ++q) xv[rr][q] = bf2f((unsigned short)u[q]);
            } else {
#pragma unroll
                for (int q = 0; q < 8; ++q) xv[rr][q] = 0.f;
            }
        }
        bh8 o;
#pragma unroll
        for (int q = 0; q < 8; ++q) {
            const f32x4 w4 = *(const f32x4*)&cw[(dg + q) * 4];
            float a = cb[dg + q] + w4[0] * xv[0][q] + w4[1] * xv[1][q]
                                 + w4[2] * xv[2][q] + w4[3] * xv[3][q];
            a = a / (1.f + __expf(-a));
            o[q] = (short)f2bf(a);
        }
        *(bh8*)&As[t_o * 32 + dl] = o;
        __syncthreads();
        const int row2 = lane & 15, q8 = (lane >> 4) * 8;
        bh8 af[2], bfr[2];
#pragma unroll
        for (int i = 0; i < 2; ++i) af[i] = *(const bh8*)&As[(wm * 32 + i * 16 + row2) * 32 + q8];
#pragma unroll
        for (int i = 0; i < 2; ++i) bfr[i] = *(const bh8*)&Bs[(wn * 32 + i * 16 + row2) * 32 + q8];
#pragma unroll
        for (int i = 0; i < 2; ++i)
#pragma unroll
            for (int j = 0; j < 2; ++j)
                acc[i][j] = __builtin_amdgcn_mfma_f32_16x16x32_bf16(af[i], bfr[j], acc[i][j], 0, 0, 0);
        __syncthreads();
    }
    const int crow = (lane >> 4) * 4, ccol = lane & 15;
#pragma unroll
    for (int i = 0; i < 2; ++i)
#pragma unroll
        for (int j = 0; j < 2; ++j)
#pragma unroll
            for (int r = 0; r < 4; ++r) {
                long gr = arow0 + wm * 32 + i * 16 + crow + r;
                long gc = bcol0 + wn * 32 + j * 16 + ccol;
                atomicAdd(&C[gr * 128 + gc], acc[i][j][r]);
            }
}

// ---------------- dt_proj fused: Dbl f32 -> lowrank bf16 (pad) @ Wdt^T + bias -> softplus -> bf16 ----------------
__global__ __launch_bounds__(256) void k_dtproj(const float* __restrict__ Dbl,
                                                const unsigned short* __restrict__ Wdt,
                                                const float* __restrict__ bias,
                                                unsigned short* __restrict__ Dt) {
    __shared__ __align__(16) unsigned short As[2 * 64 * 32];
    __shared__ __align__(16) unsigned short Bs[2 * 64 * 32];
    const int tid = threadIdx.x;
    const int lane = tid & 63, wid = tid >> 6;
    const int wm = wid >> 1, wn = wid & 1;
    const long arow0 = (long)blockIdx.y * 64;
    const long bcol0 = (long)blockIdx.x * 64;

    {
        int r = tid >> 2;
        int cs = (tid & 3) * 16;
        unsigned short tmp[16];
#pragma unroll
        for (int q = 0; q < 4; ++q) {
            int col0 = cs + q * 4;
            if (col0 < 48) {
                f32x4 v = *(const f32x4*)&Dbl[(arow0 + r) * 128 + col0];
#pragma unroll
                for (int j = 0; j < 4; ++j) tmp[q * 4 + j] = f2bf(v[j]);
            } else {
#pragma unroll
                for (int j = 0; j < 4; ++j) tmp[q * 4 + j] = 0;
            }
        }
        int p = cs >> 5;
        int cp = cs & 31;
        *(bh8*)&As[p * 2048 + r * 32 + cp]     = *(bh8*)&tmp[0];
        *(bh8*)&As[p * 2048 + r * 32 + cp + 8] = *(bh8*)&tmp[8];
    }
#pragma unroll
    for (int j = 0; j < 2; ++j) {
        int chunk = tid + j * 256;
        int p = chunk >> 8;
        int rem = chunk & 255;
        int row = rem >> 2;
        int c4 = rem & 3;
        glds16(&Wdt[(bcol0 + row) * 64 + p * 32 + c4 * 8], &Bs[chunk * 8]);
    }
    __syncthreads();

    const int row2 = lane & 15, q8 = (lane >> 4) * 8;
    f32x4 acc[2][2] = {};
#pragma unroll
    for (int p = 0; p < 2; ++p) {
        bh8 af[2], bfr[2];
#pragma unroll
        for (int i = 0; i < 2; ++i) af[i] = *(const bh8*)&As[p * 2048 + (wm * 32 + i * 16 + row2) * 32 + q8];
#pragma unroll
        for (int i = 0; i < 2; ++i) bfr[i] = *(const bh8*)&Bs[p * 2048 + (wn * 32 + i * 16 + row2) * 32 + q8];
#pragma unroll
        for (int i = 0; i < 2; ++i)
#pragma unroll
            for (int j = 0; j < 2; ++j)
                acc[i][j] = __builtin_amdgcn_mfma_f32_16x16x32_bf16(af[i], bfr[j], acc[i][j], 0, 0, 0);
    }
    const int crow = (lane >> 4) * 4, ccol = lane & 15;
#pragma unroll
    for (int i = 0; i < 2; ++i)
#pragma unroll
        for (int j = 0; j < 2; ++j)
#pragma unroll
            for (int r = 0; r < 4; ++r) {
                long gr = arow0 + wm * 32 + i * 16 + crow + r;
                long gc = bcol0 + wn * 32 + j * 16 + ccol;
                float v = acc[i][j][r] + bias[gc];
                v = (v > 20.f) ? v : log1pf(__expf(v));
                Dt[gr * DI + gc] = f2bf(v);
            }
}

// ---------------- out_proj GEMM: 64x64 tile, XCD-swizzled; grid (12,64) ----------------
__global__ __launch_bounds__(256) void k_outproj(const unsigned short* __restrict__ A,
                                                 const unsigned short* __restrict__ B,
                                                 float* __restrict__ C) {
    __shared__ __align__(16) unsigned short As[64 * 32];
    __shared__ __align__(16) unsigned short Bs[64 * 32];
    const int tid = threadIdx.x;
    const int lane = tid & 63, wid = tid >> 6;
    const int wm = wid >> 1, wn = wid & 1;
    const int id = blockIdx.y * 12 + blockIdx.x;
    const int xcd = id & 7, loc = id >> 3;
    const int bx = (xcd & 1) * 6 + loc % 6;
    const int by = (xcd >> 1) * 16 + loc / 6;
    const long arow0 = (long)by * 64;
    const long bcol0 = (long)bx * 64;
    const int r16 = lane >> 2;
    const int c8  = (lane & 3) * 8;
    f32x4 acc[2][2] = {};

    for (int k0 = 0; k0 < DI; k0 += 32) {
        int row = wid * 16 + r16;
        glds16(&A[(arow0 + row) * DI + k0 + c8], &As[wid * 512]);
        glds16(&B[(bcol0 + row) * DI + k0 + c8], &Bs[wid * 512]);
        __syncthreads();
        const int row2 = lane & 15, q8 = (lane >> 4) * 8;
        bh8 af[2], bfr[2];
#pragma unroll
        for (int i = 0; i < 2; ++i) af[i] = *(const bh8*)&As[(wm * 32 + i * 16 + row2) * 32 + q8];
#pragma unroll
        for (int i = 0; i < 2; ++i) bfr[i] = *(const bh8*)&Bs[(wn * 32 + i * 16 + row2) * 32 + q8];
#pragma unroll
        for (int i = 0; i < 2; ++i)
#pragma unroll
            for (int j = 0; j < 2; ++j)
                acc[i][j] = __builtin_amdgcn_mfma_f32_16x16x32_bf16(af[i], bfr[j], acc[i][j], 0, 0, 0);
        __syncthreads();
    }
    const int crow = (lane >> 4) * 4, ccol = lane & 15;
#pragma unroll
    for (int i = 0; i < 2; ++i)
#pragma unroll
        for (int j = 0; j < 2; ++j)
#pragma unroll
            for (int r = 0; r < 4; ++r) {
                long gr = arow0 + wm * 32 + i * 16 + crow + r;
                long gc = bcol0 + wn * 32 + j * 16 + ccol;
                C[gr * DM + gc] = acc[i][j][r];
            }
}

// ---------------- chunked selective scan (conv fused; B/C staged in LDS) ----------------
// phase 1: per (b,chunk,d): local scan from h=0; store final h and sum(dt)
__global__ __launch_bounds__(256) void k_scan1(const unsigned short* __restrict__ dt,
                                               const unsigned short* __restrict__ xz,
                                               const float* __restrict__ dbl,
                                               const float* __restrict__ An,
                                               const float* __restrict__ cw,
                                               const float* __restrict__ cb,
                                               float* __restrict__ hch,
                                               float* __restrict__ sdtb) {
    __shared__ __align__(16) float Bsh[CLEN * 16];   // [t][n], 64B rows
    const int tid = threadIdx.x;
    const int lane = tid & 63, w = tid >> 6;
    const int db = blockIdx.x % 6;
    const int c  = (blockIdx.x / 6) % NCH;
    const int b  = blockIdx.x / (6 * NCH);
    const int d  = db * 256 + tid;
    const int t0 = c * CLEN;
    const long rowb = (long)b * T_LEN + t0;
    // stage B chunk: waves 0,1 each cover 16 t (64 lanes x 16B = 1KB)
    if (w < 2) {
        int t = w * 16 + (lane >> 2);
        int nq = lane & 3;
        glds16(&dbl[(rowb + t) * 128 + 48 + nq * 4], &Bsh[w * 256]);
    }
    float h[DS], An_r[DS];
    const f32x4* Ap = (const f32x4*)(An + (long)d * DS);
#pragma unroll
    for (int q = 0; q < 4; ++q) {
        f32x4 a4 = Ap[q];
#pragma unroll
        for (int j = 0; j < 4; ++j) { An_r[q * 4 + j] = a4[j]; h[q * 4 + j] = 0.f; }
    }
    const f32x4 w4 = *(const f32x4*)&cw[d * 4];
    const float cbv = cb[d];
    float x1, x2, x3;
    if (c == 0) { x1 = x2 = x3 = 0.f; }
    else {
        x1 = bf2f(xz[(rowb - 1) * 3072 + d]);
        x2 = bf2f(xz[(rowb - 2) * 3072 + d]);
        x3 = bf2f(xz[(rowb - 3) * 3072 + d]);
    }
    __syncthreads();
    float sdt = 0.f;
#pragma unroll 4
    for (int s = 0; s < CLEN; ++s) {
        long bt = rowb + s;
        float xt = bf2f(xz[bt * 3072 + d]);
        float a = cbv + w4[0] * x3 + w4[1] * x2 + w4[2] * x1 + w4[3] * xt;
        float xcv = a / (1.f + __expf(-a));
        x3 = x2; x2 = x1; x1 = xt;
        float dtv = bf2f(dt[bt * DI + d]);
        const f32x4* bp = (const f32x4*)&Bsh[s * 16];
        float du = dtv * xcv;
        sdt += dtv;
#pragma unroll
        for (int q = 0; q < 4; ++q) {
            f32x4 b4 = bp[q];
#pragma unroll
            for (int j = 0; j < 4; ++j) {
                int n = q * 4 + j;
                h[n] = __expf(An_r[n] * dtv) * h[n] + du * b4[j];
            }
        }
    }
    long o = (((long)b * NCH + c) * DI + d) * DS;
    f32x4* hp = (f32x4*)(hch + o);
#pragma unroll
    for (int q = 0; q < 4; ++q) {
        f32x4 h4;
#pragma unroll
        for (int j = 0; j < 4; ++j) h4[j] = h[q * 4 + j];
        hp[q] = h4;
    }
    sdtb[((long)b * NCH + c) * DI + d] = sdt;
}

// phase 2a: within-segment combine over SEGC chunks; prefix in place + seg aggregates
__global__ __launch_bounds__(256) void k_scan2a(float* __restrict__ hbuf,
                                                const float* __restrict__ sdtb,
                                                const float* __restrict__ An,
                                                float* __restrict__ cum,
                                                float* __restrict__ Gseg,
                                                float* __restrict__ Sseg) {
    long gid = (long)blockIdx.x * 256 + threadIdx.x;
    int n = (int)(gid & 15);
    long t = gid >> 4;
    int d  = (int)(t % DI);
    int sg = (int)((t / DI) & (NSEG - 1));
    int b  = (int)(t / (DI * NSEG));
    float an = An[(long)d * DS + n];
    float h = 0.f, cs = 0.f;
    for (int i = 0; i < SEGC; ++i) {
        int c = sg * SEGC + i;
        long rowi = ((long)b * NCH + c) * DI + d;
        long idx = rowi * DS + n;
        float sdt = sdtb[rowi];
        float g = hbuf[idx];
        hbuf[idx] = h;
        if (n == 0) cum[rowi] = cs;
        h = __expf(an * sdt) * h + g;
        cs += sdt;
    }
    long gi = (((long)b * NSEG + sg) * DI + d) * DS + n;
    Gseg[gi] = h;
    if (n == 0) Sseg[((long)b * NSEG + sg) * DI + d] = cs;
}

// phase 3: combine <=7 segment aggregates inline; rescan with conv fused;
// fuse y=(scan + xc*D)*silu(z); emit bf16. B/C staged in LDS.
__global__ __launch_bounds__(256) void k_scan3(const unsigned short* __restrict__ dt,
                                               const unsigned short* __restrict__ xz,
                                               const float* __restrict__ dbl,
                                               const float* __restrict__ An,
                                               const float* __restrict__ cw,
                                               const float* __restrict__ cb,
                                               const float* __restrict__ Dp,
                                               const float* __restrict__ hpref,
                                               const float* __restrict__ cum,
                                               const float* __restrict__ Gseg,
                                               const float* __restrict__ Sseg,
                                               unsigned short* __restrict__ ybf) {
    __shared__ __align__(16) float Bsh[CLEN * 16];
    __shared__ __align__(16) float Csh[CLEN * 16];
    const int tid = threadIdx.x;
    const int lane = tid & 63, w = tid >> 6;
    const int db = blockIdx.x % 6;
    const int c  = (blockIdx.x / 6) % NCH;
    const int b  = blockIdx.x / (6 * NCH);
    const int d  = db * 256 + tid;
    const int t0 = c * CLEN;
    const int sg = c / SEGC;
    const long rowb = (long)b * T_LEN + t0;
    // stage B (waves 0,1) and C (waves 2,3)
    if (w < 2) {
        int t = w * 16 + (lane >> 2);
        glds16(&dbl[(rowb + t) * 128 + 48 + (lane & 3) * 4], &Bsh[w * 256]);
    } else {
        int t = (w - 2) * 16 + (lane >> 2);
        glds16(&dbl[(rowb + t) * 128 + 64 + (lane & 3) * 4], &Csh[(w - 2) * 256]);
    }
    float h[DS], An_r[DS];
    long rowi = ((long)b * NCH + c) * DI + d;
    long o = rowi * DS;
    const float cs = cum[rowi];
    const f32x4* Ap = (const f32x4*)(An + (long)d * DS);
#pragma unroll
    for (int q = 0; q < 4; ++q) {
        f32x4 a4 = Ap[q];
#pragma unroll
        for (int j = 0; j < 4; ++j) An_r[q * 4 + j] = a4[j];
    }
    // fold of scan2b: combine segments 0..sg-1
    float Hn[DS];
#pragma unroll
    for (int n = 0; n < DS; ++n) Hn[n] = 0.f;
    for (int s2 = 0; s2 < sg; ++s2) {
        long gi = (((long)b * NSEG + s2) * DI + d) * DS;
        float S = Sseg[((long)b * NSEG + s2) * DI + d];
        const f32x4* Gp = (const f32x4*)(Gseg + gi);
#pragma unroll
        for (int q = 0; q < 4; ++q) {
            f32x4 g4 = Gp[q];
#pragma unroll
            for (int j = 0; j < 4; ++j) {
                int n = q * 4 + j;
                Hn[n] = __expf(An_r[n] * S) * Hn[n] + g4[j];
            }
        }
    }
    const f32x4* Pp = (const f32x4*)(hpref + o);
#pragma unroll
    for (int q = 0; q < 4; ++q) {
        f32x4 p4 = Pp[q];
#pragma unroll
        for (int j = 0; j < 4; ++j) {
            int n = q * 4 + j;
            h[n] = __expf(An_r[n] * cs) * Hn[n] + p4[j];
        }
    }
    const float dcoef = Dp[d];
    const f32x4 w4 = *(const f32x4*)&cw[d * 4];
    const float cbv = cb[d];
    float x1, x2, x3;
    if (c == 0) { x1 = x2 = x3 = 0.f; }
    else {
        x1 = bf2f(xz[(rowb - 1) * 3072 + d]);
        x2 = bf2f(xz[(rowb - 2) * 3072 + d]);
        x3 = bf2f(xz[(rowb - 3) * 3072 + d]);
    }
    __syncthreads();
#pragma unroll 4
    for (int s = 0; s < CLEN; ++s) {
        long bt = rowb + s;
        float xt = bf2f(xz[bt * 3072 + d]);
        float a = cbv + w4[0] * x3 + w4[1] * x2 + w4[2] * x1 + w4[3] * xt;
        float xcv = a / (1.f + __expf(-a));
        x3 = x2; x2 = x1; x1 = xt;
        float dtv = bf2f(dt[bt * DI + d]);
        const f32x4* bp = (const f32x4*)&Bsh[s * 16];
        const f32x4* cp = (const f32x4*)&Csh[s * 16];
        float du = dtv * xcv;
        float yp[4] = {xcv * dcoef, 0.f, 0.f, 0.f};
#pragma unroll
        for (int q = 0; q < 4; ++q) {
            f32x4 b4 = bp[q], c4 = cp[q];
#pragma unroll
            for (int j = 0; j < 4; ++j) {
                int n = q * 4 + j;
                h[n] = __expf(An_r[n] * dtv) * h[n] + du * b4[j];
                yp[j] += h[n] * c4[j];
            }
        }
        float y = (yp[0] + yp[1]) + (yp[2] + yp[3]);
        float zv = bf2f(xz[bt * 3072 + DI + d]);
        y *= zv / (1.f + __expf(-zv));
        ybf[bt * DI + d] = f2bf(y);
    }
}

// ---------------- LayerNorm + residual (+ final store; zeroes Dbl for next layer) ----------------
__global__ __launch_bounds__(256) void k_ln(const float* __restrict__ prj,
                                            float* __restrict__ x,
                                            unsigned short* __restrict__ xbf,
                                            const float* __restrict__ lg,
                                            const float* __restrict__ lb,
                                            void* __restrict__ dout,
                                            float* __restrict__ dblz,
                                            int is_last, const int* __restrict__ flag) {
    __shared__ float red[8];
    const int row = blockIdx.x;
    const int tid = threadIdx.x;
    float v[3];
    float s = 0.f, s2 = 0.f;
#pragma unroll
    for (int j = 0; j < 3; ++j) {
        v[j] = prj[(long)row * DM + tid + j * 256];
        s += v[j];
        s2 += v[j] * v[j];
    }
    for (int off = 32; off; off >>= 1) {
        s  += __shfl_down(s, off, 64);
        s2 += __shfl_down(s2, off, 64);
    }
    if ((tid & 63) == 0) { red[tid >> 6] = s; red[4 + (tid >> 6)] = s2; }
    __syncthreads();
    float S  = red[0] + red[1] + red[2] + red[3];
    float S2 = red[4] + red[5] + red[6] + red[7];
    float mu = S * (1.f / DM);
    float var = S2 * (1.f / DM) - mu * mu;
    float rs = rsqrtf(var + 1e-5f);
    int bf = *flag;
#pragma unroll
    for (int j = 0; j < 3; ++j) {
        int e = tid + j * 256;
        long idx = (long)row * DM + e;
        float out = (v[j] - mu) * rs * lg[e] + lb[e] + x[idx];
        x[idx] = out;
        xbf[idx] = f2bf(out);
        if (is_last) {
            if (bf) ((unsigned short*)dout)[idx] = f2bf(out);
            else    ((float*)dout)[idx] = out;
        }
    }
    // zero Dbl (524288 f32) for next layer's split-K accumulation
    long gid = (long)row * 256 + tid;
    if (gid < 524288) dblz[gid] = 0.f;
}

// ---------------- host launcher ----------------
extern "C" void kernel_launch(void* const* d_in, const int* in_sizes, int n_in,
                              void* d_out, int out_size, void* d_ws, size_t ws_size,
                              hipStream_t stream) {
    char* ws = (char*)d_ws;
    const size_t O_FLAG = 0;
    const size_t O_WIN  = 256;
    const size_t O_WXP  = O_WIN  + 18874368;
    const size_t O_WDT  = O_WXP  + 1572864;
    const size_t O_WOUT = O_WDT  + 786432;
    const size_t O_PRM  = O_WOUT + 9437184;
    const size_t O_XBF  = O_PRM  + 589824;
    const size_t O_XF   = O_XBF  + 6291456;
    const size_t O_XZ   = O_XF   + 12582912;   // bf16 [4096,3072]; f32 Prj aliases
    const size_t O_DBL  = O_XZ   + 25165824;   // f32 [4096,128]
    const size_t O_DT   = O_DBL  + 2097152;    // bf16 [4096,1536]
    const size_t O_HCH  = O_DT   + 12582912;   // f32 [2,64,1536,16]
    const size_t O_SDT  = O_HCH  + 12582912;
    const size_t O_CUM  = O_SDT  + 786432;
    const size_t O_GSEG = O_CUM  + 786432;
    const size_t O_SSEG = O_GSEG + 1572864;
    const size_t O_YBF  = O_SSEG + 98304;

    int* flag = (int*)(ws + O_FLAG);
    unsigned short* Win  = (unsigned short*)(ws + O_WIN);
    unsigned short* Wxp  = (unsigned short*)(ws + O_WXP);
    unsigned short* Wdt  = (unsigned short*)(ws + O_WDT);
    unsigned short* Wout = (unsigned short*)(ws + O_WOUT);
    float* prm = (float*)(ws + O_PRM);
    unsigned short* Xbf = (unsigned short*)(ws + O_XBF);
    float* Xf  = (float*)(ws + O_XF);
    unsigned short* Xz = (unsigned short*)(ws + O_XZ);
    float* Dbl = (float*)(ws + O_DBL);
    unsigned short* Dt = (unsigned short*)(ws + O_DT);
    float* Hch = (float*)(ws + O_HCH);
    float* Sdt = (float*)(ws + O_SDT);
    float* Cum = (float*)(ws + O_CUM);
    float* Gsg = (float*)(ws + O_GSEG);
    float* Ssg = (float*)(ws + O_SSEG);
    unsigned short* Ybf = (unsigned short*)(ws + O_YBF);
    float* Prj = (float*)(ws + O_XZ);   // alias: z consumed by scan3 before out_proj writes

    k_sniff<<<1, 256, 0, stream>>>((const unsigned short*)d_in[0], flag);
    k_prep<<<9352, 256, 0, stream>>>(d_in[0], d_in[1], d_in[9], d_in[4], d_in[5],
                                     d_in[6], d_in[7], d_in[8], d_in[2], d_in[3],
                                     d_in[10], d_in[11],
                                     Xbf, Xf, Win, Wout, Wxp, Wdt, prm, Dbl, flag);

    for (int l = 0; l < 4; ++l) {
        const unsigned short* winL  = Win  + (size_t)l * 3072 * 768;
        const unsigned short* wxpL  = Wxp  + (size_t)l * 128 * 1536;
        const unsigned short* wdtL  = Wdt  + (size_t)l * 1536 * 64;
        const unsigned short* woutL = Wout + (size_t)l * 768 * 1536;
        const float* cwL  = prm + OFF_CW  + (size_t)l * DI * 4;
        const float* cbL  = prm + OFF_CB  + (size_t)l * DI;
        const float* dtbL = prm + OFF_DTB + (size_t)l * DI;
        const float* anL  = prm + OFF_A   + (size_t)l * DI * DS;
        const float* dpL  = prm + OFF_DP  + (size_t)l * DI;
        const float* lgL  = prm + OFF_LG  + (size_t)l * DM;
        const float* lbL  = prm + OFF_LB  + (size_t)l * DM;

        k_gemm128<<<dim3(24, 32), 256, 0, stream>>>(Xbf, winL, Xz, NROWS, 2 * DI, DM);
        k_xproj<<<dim3(2, 64, 4), 256, 0, stream>>>(Xz, wxpL, cwL, cbL, Dbl);
        k_dtproj<<<dim3(24, 64), 256, 0, stream>>>(Dbl, wdtL, dtbL, Dt);
        k_scan1<<<BB * NCH * 6, 256, 0, stream>>>(Dt, Xz, Dbl, anL, cwL, cbL, Hch, Sdt);
        k_scan2a<<<1536, 256, 0, stream>>>(Hch, Sdt, anL, Cum, Gsg, Ssg);
        k_scan3<<<BB * NCH * 6, 256, 0, stream>>>(Dt, Xz, Dbl, anL, cwL, cbL, dpL,
                                                  Hch, Cum, Gsg, Ssg, Ybf);
        k_outproj<<<dim3(12, 64), 256, 0, stream>>>(Ybf, woutL, Prj);
        k_ln<<<4096, 256, 0, stream>>>(Prj, Xf, Xbf, lgL, lbL, d_out, Dbl,
                                       (l == 3) ? 1 : 0, flag);
    }
}

// Round 7
// 864.396 us; speedup vs baseline: 1.1211x; 1.0818x over previous
//
#include <hip/hip_runtime.h>

// ---------------- constants ----------------
#define T_LEN 2048
#define DM    768
#define DI    1536
#define DS    16
#define BB    2
#define NROWS (BB * T_LEN)   // 4096
#define NCH   64             // scan chunks per sequence
#define CLEN  32             // chunk length (768 scan blocks = 3/CU)
#define NSEG  8              // segments
#define SEGC  8              // chunks per segment

// param-buffer (f32) segment offsets (elements)
#define OFF_DTB 0
#define OFF_A   6144
#define OFF_DP  104448
#define OFF_CW  110592
#define OFF_CB  135168
#define OFF_LG  141312
#define OFF_LB  144384
#define PRM_TOT 147456

typedef __attribute__((ext_vector_type(8))) short bh8;
typedef __attribute__((ext_vector_type(4))) float f32x4;

typedef const __attribute__((address_space(1))) void as1_void;
typedef __attribute__((address_space(3))) void as3_void;

__device__ __forceinline__ void glds16(const void* g, void* l) {
    __builtin_amdgcn_global_load_lds((as1_void*)g, (as3_void*)l, 16, 0, 0);
}

// ---------------- small helpers ----------------
__device__ __forceinline__ float bf2f(unsigned short u) {
    return __uint_as_float(((unsigned)u) << 16);
}
__device__ __forceinline__ unsigned short f2bf(float f) {
    unsigned u = __float_as_uint(f);
    u += 0x7FFFu + ((u >> 16) & 1u);   // RNE
    return (unsigned short)(u >> 16);
}

__device__ __forceinline__ void ld8(const void* p, long e0, int bf, float* v) {
    if (bf) {
        bh8 u = *(const bh8*)((const unsigned short*)p + e0);
#pragma unroll
        for (int j = 0; j < 8; ++j) v[j] = bf2f((unsigned short)u[j]);
    } else {
        const f32x4* q = (const f32x4*)((const float*)p + e0);
        f32x4 a = q[0], b = q[1];
#pragma unroll
        for (int j = 0; j < 4; ++j) { v[j] = a[j]; v[4 + j] = b[j]; }
    }
}

__device__ __forceinline__ void cp8(unsigned short* dst, long de0,
                                    const void* src, long se0, int bf) {
    if (bf) {
        *(bh8*)&dst[de0] = *(const bh8*)((const unsigned short*)src + se0);
    } else {
        const f32x4* q = (const f32x4*)((const float*)src + se0);
        f32x4 a = q[0], b = q[1];
        bh8 o;
#pragma unroll
        for (int j = 0; j < 4; ++j) { o[j] = (short)f2bf(a[j]); o[4 + j] = (short)f2bf(b[j]); }
        *(bh8*)&dst[de0] = o;
    }
}

// ---------------- dtype sniffer ----------------
__global__ void k_sniff(const unsigned short* __restrict__ x, int* __restrict__ flag) {
    __shared__ int cnt[4];
    int tid = threadIdx.x;
    int local = 0;
#pragma unroll
    for (int j = 0; j < 4; ++j) {
        unsigned short u = x[tid * 4 + j];
        int e = (u >> 7) & 0xFF;
        if (e >= 100 && e <= 140) local++;
    }
    for (int off = 32; off; off >>= 1) local += __shfl_down(local, off, 64);
    if ((tid & 63) == 0) cnt[tid >> 6] = local;
    __syncthreads();
    if (tid == 0) {
        int tot = cnt[0] + cnt[1] + cnt[2] + cnt[3];
        *flag = (tot >= 900) ? 1 : 0;
    }
}

// ---------------- fused preamble conversion (8 elems / thread, 16B IO) ----------------
// extra tail range zeroes Dbl (split-K accumulator) for layer 0
__global__ void k_prep(const void* in_x, const void* in_inw, const void* in_ow,
                       const void* in_xpw, const void* in_dtw,
                       const void* dtb, const void* alog, const void* dpar,
                       const void* cw, const void* cb, const void* lg, const void* lb,
                       unsigned short* __restrict__ xbf, float* __restrict__ xf,
                       unsigned short* __restrict__ Win, unsigned short* __restrict__ Wout,
                       unsigned short* __restrict__ Wxp, unsigned short* __restrict__ Wdt,
                       float* __restrict__ prm, float* __restrict__ dblz,
                       const int* __restrict__ flag) {
    const long G0 = 393216L;            // x groups (3145728/8)
    const long G1 = G0 + 1179648L;      // in_proj_w
    const long G2 = G1 + 589824L;       // out_proj_w
    const long G3 = G2 + 98304L;        // x_proj_w padded
    const long G4 = G3 + 49152L;        // dt_proj_w padded
    const long G5 = G4 + 18432L;        // params
    const long G6 = G5 + 65536L;        // Dbl zero (524288 f32)
    int bf = *flag;
    long g = (long)blockIdx.x * 256 + threadIdx.x;
    if (g >= G6) return;
    if (g < G0) {
        long e0 = g * 8;
        float v[8];
        ld8(in_x, e0, bf, v);
        bh8 o;
#pragma unroll
        for (int j = 0; j < 8; ++j) o[j] = (short)f2bf(v[j]);
        *(bh8*)&xbf[e0] = o;
        f32x4 a, b;
#pragma unroll
        for (int j = 0; j < 4; ++j) { a[j] = v[j]; b[j] = v[4 + j]; }
        ((f32x4*)&xf[e0])[0] = a;
        ((f32x4*)&xf[e0])[1] = b;
    } else if (g < G1) {
        long e0 = (g - G0) * 8;
        cp8(Win, e0, in_inw, e0, bf);
    } else if (g < G2) {
        long e0 = (g - G1) * 8;
        cp8(Wout, e0, in_ow, e0, bf);
    } else if (g < G3) {
        long e0 = (g - G2) * 8;
        int c = (int)(e0 % 1536);
        long rl = e0 / 1536;
        int r = (int)(rl % 128);
        int l = (int)(rl / 128);
        if (r < 80) cp8(Wxp, e0, in_xpw, ((long)l * 80 + r) * 1536 + c, bf);
        else        *(bh8*)&Wxp[e0] = (bh8)(short)0;
    } else if (g < G4) {
        long e0 = (g - G3) * 8;
        int c = (int)(e0 & 63);
        long rl = e0 >> 6;
        int d = (int)(rl % 1536);
        int l = (int)(rl / 1536);
        if (c < 48) cp8(Wdt, e0, in_dtw, ((long)l * 1536 + d) * 48 + c, bf);
        else        *(bh8*)&Wdt[e0] = (bh8)(short)0;
    } else if (g < G5) {
        long e0 = (g - G4) * 8;
        float v[8];
        if (e0 < OFF_A)        ld8(dtb,  e0 - OFF_DTB, bf, v);
        else if (e0 < OFF_DP) {
            ld8(alog, e0 - OFF_A, bf, v);
#pragma unroll
            for (int j = 0; j < 8; ++j) v[j] = -__expf(v[j]);
        }
        else if (e0 < OFF_CW)  ld8(dpar, e0 - OFF_DP, bf, v);
        else if (e0 < OFF_CB)  ld8(cw,   e0 - OFF_CW, bf, v);
        else if (e0 < OFF_LG)  ld8(cb,   e0 - OFF_CB, bf, v);
        else if (e0 < OFF_LB)  ld8(lg,   e0 - OFF_LG, bf, v);
        else                   ld8(lb,   e0 - OFF_LB, bf, v);
        f32x4 a, b;
#pragma unroll
        for (int j = 0; j < 4; ++j) { a[j] = v[j]; b[j] = v[4 + j]; }
        ((f32x4*)&prm[e0])[0] = a;
        ((f32x4*)&prm[e0])[1] = b;
    } else {
        long e0 = (g - G5) * 8;
        f32x4 z = {0.f, 0.f, 0.f, 0.f};
        ((f32x4*)&dblz[e0])[0] = z;
        ((f32x4*)&dblz[e0])[1] = z;
    }
}

// ---------------- in_proj GEMM: 128x128 tile, XCD-swizzled, bf16 in, bf16 out ----------------
__global__ __launch_bounds__(256) void k_gemm128(const unsigned short* __restrict__ A,
                                                 const unsigned short* __restrict__ B,
                                                 unsigned short* __restrict__ C,
                                                 int M, int N, int K) {
    __shared__ __align__(16) unsigned short As[128 * 32];
    __shared__ __align__(16) unsigned short Bs[128 * 32];
    const int tid = threadIdx.x;
    const int lane = tid & 63, wid = tid >> 6;
    const int wm = wid >> 1, wn = wid & 1;
    const int id = blockIdx.y * 24 + blockIdx.x;
    const int xcd = id & 7, loc = id >> 3;
    const int bx = (xcd & 1) * 12 + loc % 12;
    const int by = (xcd >> 1) * 8 + loc / 12;
    const long arow0 = (long)by * 128;
    const long bcol0 = (long)bx * 128;
    const int r16 = lane >> 2;
    const int c8  = (lane & 3) * 8;
    f32x4 acc[4][4] = {};

    for (int k0 = 0; k0 < K; k0 += 32) {
#pragma unroll
        for (int j = 0; j < 2; ++j) {
            int chunk = wid + j * 4;
            int row = chunk * 16 + r16;
            glds16(&A[(arow0 + row) * K + k0 + c8], &As[chunk * 512]);
            glds16(&B[(bcol0 + row) * K + k0 + c8], &Bs[chunk * 512]);
        }
        __syncthreads();
        const int row = lane & 15, q8 = (lane >> 4) * 8;
        bh8 af[4], bfr[4];
#pragma unroll
        for (int i = 0; i < 4; ++i) af[i] = *(const bh8*)&As[(wm * 64 + i * 16 + row) * 32 + q8];
#pragma unroll
        for (int i = 0; i < 4; ++i) bfr[i] = *(const bh8*)&Bs[(wn * 64 + i * 16 + row) * 32 + q8];
#pragma unroll
        for (int i = 0; i < 4; ++i)
#pragma unroll
            for (int j = 0; j < 4; ++j)
                acc[i][j] = __builtin_amdgcn_mfma_f32_16x16x32_bf16(af[i], bfr[j], acc[i][j], 0, 0, 0);
        __syncthreads();
    }
    const int crow = (lane >> 4) * 4, ccol = lane & 15;
#pragma unroll
    for (int i = 0; i < 4; ++i)
#pragma unroll
        for (int j = 0; j < 4; ++j)
#pragma unroll
            for (int r = 0; r < 4; ++r) {
                long gr = arow0 + wm * 64 + i * 16 + crow + r;
                long gc = bcol0 + wn * 64 + j * 16 + ccol;
                C[gr * N + gc] = f2bf(acc[i][j][r]);
            }
}

// ---------------- tiled depthwise causal conv + SiLU (bf16 in/out) ----------------
// grid (24 d-tiles, 32 bt-tiles of 128)
__global__ __launch_bounds__(256) void k_conv(const unsigned short* __restrict__ xz,
                                              const float* __restrict__ cw,
                                              const float* __restrict__ cb,
                                              unsigned short* __restrict__ xcbf) {
    __shared__ float tile[131 * 64];
    const int tid = threadIdx.x;
    const int d0 = blockIdx.x * 64;
    const long t0 = (long)blockIdx.y * 128;
    const bool seqstart = ((int)t0 & (T_LEN - 1)) == 0;
    for (int j = tid; j < 131 * 64; j += 256) {
        int row = j >> 6, col = j & 63;
        float v = 0.f;
        if (!(seqstart && row < 3)) v = bf2f(xz[(t0 - 3 + row) * 3072 + d0 + col]);
        tile[j] = v;
    }
    __syncthreads();
    const int d = tid & 63, tl0 = tid >> 6;
    const int dg = d0 + d;
    const float w0 = cw[dg * 4 + 0], w1 = cw[dg * 4 + 1];
    const float w2 = cw[dg * 4 + 2], w3 = cw[dg * 4 + 3];
    const float bias = cb[dg];
    for (int tt = tl0; tt < 128; tt += 4) {
        float acc = bias + w0 * tile[tt * 64 + d] + w1 * tile[(tt + 1) * 64 + d]
                         + w2 * tile[(tt + 2) * 64 + d] + w3 * tile[(tt + 3) * 64 + d];
        float s = acc / (1.f + __expf(-acc));
        xcbf[(t0 + tt) * DI + dg] = f2bf(s);
    }
}

// ---------------- x_proj GEMM: split-K=4, atomic f32 accum; grid (2, 64, 4) ----------------
__global__ __launch_bounds__(256) void k_xproj(const unsigned short* __restrict__ A,
                                               const unsigned short* __restrict__ B,
                                               float* __restrict__ C) {
    __shared__ __align__(16) unsigned short As[64 * 32];
    __shared__ __align__(16) unsigned short Bs[64 * 32];
    const int tid = threadIdx.x;
    const int lane = tid & 63, wid = tid >> 6;
    const int wm = wid >> 1, wn = wid & 1;
    const long arow0 = (long)blockIdx.y * 64;
    const long bcol0 = (long)blockIdx.x * 64;
    const int kbase = blockIdx.z * 384;
    const int r16 = lane >> 2;
    const int c8  = (lane & 3) * 8;
    f32x4 acc[2][2] = {};

    for (int kk = 0; kk < 384; kk += 32) {
        int k0 = kbase + kk;
        int row = wid * 16 + r16;
        glds16(&A[(arow0 + row) * DI + k0 + c8], &As[wid * 512]);
        glds16(&B[(bcol0 + row) * DI + k0 + c8], &Bs[wid * 512]);
        __syncthreads();
        const int row2 = lane & 15, q8 = (lane >> 4) * 8;
        bh8 af[2], bfr[2];
#pragma unroll
        for (int i = 0; i < 2; ++i) af[i] = *(const bh8*)&As[(wm * 32 + i * 16 + row2) * 32 + q8];
#pragma unroll
        for (int i = 0; i < 2; ++i) bfr[i] = *(const bh8*)&Bs[(wn * 32 + i * 16 + row2) * 32 + q8];
#pragma unroll
        for (int i = 0; i < 2; ++i)
#pragma unroll
            for (int j = 0; j < 2; ++j)
                acc[i][j] = __builtin_amdgcn_mfma_f32_16x16x32_bf16(af[i], bfr[j], acc[i][j], 0, 0, 0);
        __syncthreads();
    }
    const int crow = (lane >> 4) * 4, ccol = lane & 15;
#pragma unroll
    for (int i = 0; i < 2; ++i)
#pragma unroll
        for (int j = 0; j < 2; ++j)
#pragma unroll
            for (int r = 0; r < 4; ++r) {
                long gr = arow0 + wm * 32 + i * 16 + crow + r;
                long gc = bcol0 + wn * 32 + j * 16 + ccol;
                atomicAdd(&C[gr * 128 + gc], acc[i][j][r]);
            }
}

// ---------------- dt_proj fused: Dbl f32 -> lowrank bf16 (pad) @ Wdt^T + bias -> softplus -> bf16 ----------------
__global__ __launch_bounds__(256) void k_dtproj(const float* __restrict__ Dbl,
                                                const unsigned short* __restrict__ Wdt,
                                                const float* __restrict__ bias,
                                                unsigned short* __restrict__ Dt) {
    __shared__ __align__(16) unsigned short As[2 * 64 * 32];
    __shared__ __align__(16) unsigned short Bs[2 * 64 * 32];
    const int tid = threadIdx.x;
    const int lane = tid & 63, wid = tid >> 6;
    const int wm = wid >> 1, wn = wid & 1;
    const long arow0 = (long)blockIdx.y * 64;
    const long bcol0 = (long)blockIdx.x * 64;

    {
        int r = tid >> 2;
        int cs = (tid & 3) * 16;
        unsigned short tmp[16];
#pragma unroll
        for (int q = 0; q < 4; ++q) {
            int col0 = cs + q * 4;
            if (col0 < 48) {
                f32x4 v = *(const f32x4*)&Dbl[(arow0 + r) * 128 + col0];
#pragma unroll
                for (int j = 0; j < 4; ++j) tmp[q * 4 + j] = f2bf(v[j]);
            } else {
#pragma unroll
                for (int j = 0; j < 4; ++j) tmp[q * 4 + j] = 0;
            }
        }
        int p = cs >> 5;
        int cp = cs & 31;
        *(bh8*)&As[p * 2048 + r * 32 + cp]     = *(bh8*)&tmp[0];
        *(bh8*)&As[p * 2048 + r * 32 + cp + 8] = *(bh8*)&tmp[8];
    }
#pragma unroll
    for (int j = 0; j < 2; ++j) {
        int chunk = tid + j * 256;
        int p = chunk >> 8;
        int rem = chunk & 255;
        int row = rem >> 2;
        int c4 = rem & 3;
        glds16(&Wdt[(bcol0 + row) * 64 + p * 32 + c4 * 8], &Bs[chunk * 8]);
    }
    __syncthreads();

    const int row2 = lane & 15, q8 = (lane >> 4) * 8;
    f32x4 acc[2][2] = {};
#pragma unroll
    for (int p = 0; p < 2; ++p) {
        bh8 af[2], bfr[2];
#pragma unroll
        for (int i = 0; i < 2; ++i) af[i] = *(const bh8*)&As[p * 2048 + (wm * 32 + i * 16 + row2) * 32 + q8];
#pragma unroll
        for (int i = 0; i < 2; ++i) bfr[i] = *(const bh8*)&Bs[p * 2048 + (wn * 32 + i * 16 + row2) * 32 + q8];
#pragma unroll
        for (int i = 0; i < 2; ++i)
#pragma unroll
            for (int j = 0; j < 2; ++j)
                acc[i][j] = __builtin_amdgcn_mfma_f32_16x16x32_bf16(af[i], bfr[j], acc[i][j], 0, 0, 0);
    }
    const int crow = (lane >> 4) * 4, ccol = lane & 15;
#pragma unroll
    for (int i = 0; i < 2; ++i)
#pragma unroll
        for (int j = 0; j < 2; ++j)
#pragma unroll
            for (int r = 0; r < 4; ++r) {
                long gr = arow0 + wm * 32 + i * 16 + crow + r;
                long gc = bcol0 + wn * 32 + j * 16 + ccol;
                float v = acc[i][j][r] + bias[gc];
                v = (v > 20.f) ? v : log1pf(__expf(v));
                Dt[gr * DI + gc] = f2bf(v);
            }
}

// ---------------- out_proj GEMM: 64x64 tile, XCD-swizzled; grid (12,64) ----------------
__global__ __launch_bounds__(256) void k_outproj(const unsigned short* __restrict__ A,
                                                 const unsigned short* __restrict__ B,
                                                 float* __restrict__ C) {
    __shared__ __align__(16) unsigned short As[64 * 32];
    __shared__ __align__(16) unsigned short Bs[64 * 32];
    const int tid = threadIdx.x;
    const int lane = tid & 63, wid = tid >> 6;
    const int wm = wid >> 1, wn = wid & 1;
    const int id = blockIdx.y * 12 + blockIdx.x;
    const int xcd = id & 7, loc = id >> 3;
    const int bx = (xcd & 1) * 6 + loc % 6;
    const int by = (xcd >> 1) * 16 + loc / 6;
    const long arow0 = (long)by * 64;
    const long bcol0 = (long)bx * 64;
    const int r16 = lane >> 2;
    const int c8  = (lane & 3) * 8;
    f32x4 acc[2][2] = {};

    for (int k0 = 0; k0 < DI; k0 += 32) {
        int row = wid * 16 + r16;
        glds16(&A[(arow0 + row) * DI + k0 + c8], &As[wid * 512]);
        glds16(&B[(bcol0 + row) * DI + k0 + c8], &Bs[wid * 512]);
        __syncthreads();
        const int row2 = lane & 15, q8 = (lane >> 4) * 8;
        bh8 af[2], bfr[2];
#pragma unroll
        for (int i = 0; i < 2; ++i) af[i] = *(const bh8*)&As[(wm * 32 + i * 16 + row2) * 32 + q8];
#pragma unroll
        for (int i = 0; i < 2; ++i) bfr[i] = *(const bh8*)&Bs[(wn * 32 + i * 16 + row2) * 32 + q8];
#pragma unroll
        for (int i = 0; i < 2; ++i)
#pragma unroll
            for (int j = 0; j < 2; ++j)
                acc[i][j] = __builtin_amdgcn_mfma_f32_16x16x32_bf16(af[i], bfr[j], acc[i][j], 0, 0, 0);
        __syncthreads();
    }
    const int crow = (lane >> 4) * 4, ccol = lane & 15;
#pragma unroll
    for (int i = 0; i < 2; ++i)
#pragma unroll
        for (int j = 0; j < 2; ++j)
#pragma unroll
            for (int r = 0; r < 4; ++r) {
                long gr = arow0 + wm * 32 + i * 16 + crow + r;
                long gc = bcol0 + wn * 32 + j * 16 + ccol;
                C[gr * DM + gc] = acc[i][j][r];
            }
}

// ---------------- chunked selective scan (xc from Xcbf; B/C staged in LDS) ----------------
// phase 1: per (b,chunk,d): local scan from h=0; store final h and sum(dt)
__global__ __launch_bounds__(256) void k_scan1(const unsigned short* __restrict__ dt,
                                               const unsigned short* __restrict__ xcbf,
                                               const float* __restrict__ dbl,
                                               const float* __restrict__ An,
                                               float* __restrict__ hch,
                                               float* __restrict__ sdtb) {
    __shared__ __align__(16) float Bsh[CLEN * 16];   // [t][n], 64B rows
    const int tid = threadIdx.x;
    const int lane = tid & 63, w = tid >> 6;
    const int db = blockIdx.x % 6;
    const int c  = (blockIdx.x / 6) % NCH;
    const int b  = blockIdx.x / (6 * NCH);
    const int d  = db * 256 + tid;
    const int t0 = c * CLEN;
    const long rowb = (long)b * T_LEN + t0;
    if (w < 2) {
        int t = w * 16 + (lane >> 2);
        glds16(&dbl[(rowb + t) * 128 + 48 + (lane & 3) * 4], &Bsh[w * 256]);
    }
    float h[DS], An_r[DS];
    const f32x4* Ap = (const f32x4*)(An + (long)d * DS);
#pragma unroll
    for (int q = 0; q < 4; ++q) {
        f32x4 a4 = Ap[q];
#pragma unroll
        for (int j = 0; j < 4; ++j) { An_r[q * 4 + j] = a4[j]; h[q * 4 + j] = 0.f; }
    }
    __syncthreads();
    float sdt = 0.f;
#pragma unroll 4
    for (int s = 0; s < CLEN; ++s) {
        long bt = rowb + s;
        float xcv = bf2f(xcbf[bt * DI + d]);
        float dtv = bf2f(dt[bt * DI + d]);
        const f32x4* bp = (const f32x4*)&Bsh[s * 16];
        float du = dtv * xcv;
        sdt += dtv;
#pragma unroll
        for (int q = 0; q < 4; ++q) {
            f32x4 b4 = bp[q];
#pragma unroll
            for (int j = 0; j < 4; ++j) {
                int n = q * 4 + j;
                h[n] = __expf(An_r[n] * dtv) * h[n] + du * b4[j];
            }
        }
    }
    long o = (((long)b * NCH + c) * DI + d) * DS;
    f32x4* hp = (f32x4*)(hch + o);
#pragma unroll
    for (int q = 0; q < 4; ++q) {
        f32x4 h4;
#pragma unroll
        for (int j = 0; j < 4; ++j) h4[j] = h[q * 4 + j];
        hp[q] = h4;
    }
    sdtb[((long)b * NCH + c) * DI + d] = sdt;
}

// phase 2a: within-segment combine over SEGC chunks; prefix in place + seg aggregates
__global__ __launch_bounds__(256) void k_scan2a(float* __restrict__ hbuf,
                                                const float* __restrict__ sdtb,
                                                const float* __restrict__ An,
                                                float* __restrict__ cum,
                                                float* __restrict__ Gseg,
                                                float* __restrict__ Sseg) {
    long gid = (long)blockIdx.x * 256 + threadIdx.x;
    int n = (int)(gid & 15);
    long t = gid >> 4;
    int d  = (int)(t % DI);
    int sg = (int)((t / DI) & (NSEG - 1));
    int b  = (int)(t / (DI * NSEG));
    float an = An[(long)d * DS + n];
    float h = 0.f, cs = 0.f;
    for (int i = 0; i < SEGC; ++i) {
        int c = sg * SEGC + i;
        long rowi = ((long)b * NCH + c) * DI + d;
        long idx = rowi * DS + n;
        float sdt = sdtb[rowi];
        float g = hbuf[idx];
        hbuf[idx] = h;
        if (n == 0) cum[rowi] = cs;
        h = __expf(an * sdt) * h + g;
        cs += sdt;
    }
    long gi = (((long)b * NSEG + sg) * DI + d) * DS + n;
    Gseg[gi] = h;
    if (n == 0) Sseg[((long)b * NSEG + sg) * DI + d] = cs;
}

// phase 3: combine <=7 segment aggregates inline; rescan; gate; emit bf16
__global__ __launch_bounds__(256) void k_scan3(const unsigned short* __restrict__ dt,
                                               const unsigned short* __restrict__ xcbf,
                                               const unsigned short* __restrict__ xz,
                                               const float* __restrict__ dbl,
                                               const float* __restrict__ An,
                                               const float* __restrict__ Dp,
                                               const float* __restrict__ hpref,
                                               const float* __restrict__ cum,
                                               const float* __restrict__ Gseg,
                                               const float* __restrict__ Sseg,
                                               unsigned short* __restrict__ ybf) {
    __shared__ __align__(16) float Bsh[CLEN * 16];
    __shared__ __align__(16) float Csh[CLEN * 16];
    const int tid = threadIdx.x;
    const int lane = tid & 63, w = tid >> 6;
    const int db = blockIdx.x % 6;
    const int c  = (blockIdx.x / 6) % NCH;
    const int b  = blockIdx.x / (6 * NCH);
    const int d  = db * 256 + tid;
    const int t0 = c * CLEN;
    const int sg = c / SEGC;
    const long rowb = (long)b * T_LEN + t0;
    if (w < 2) {
        int t = w * 16 + (lane >> 2);
        glds16(&dbl[(rowb + t) * 128 + 48 + (lane & 3) * 4], &Bsh[w * 256]);
    } else {
        int t = (w - 2) * 16 + (lane >> 2);
        glds16(&dbl[(rowb + t) * 128 + 64 + (lane & 3) * 4], &Csh[(w - 2) * 256]);
    }
    float h[DS], An_r[DS];
    long rowi = ((long)b * NCH + c) * DI + d;
    long o = rowi * DS;
    const float cs = cum[rowi];
    const f32x4* Ap = (const f32x4*)(An + (long)d * DS);
#pragma unroll
    for (int q = 0; q < 4; ++q) {
        f32x4 a4 = Ap[q];
#pragma unroll
        for (int j = 0; j < 4; ++j) An_r[q * 4 + j] = a4[j];
    }
    float Hn[DS];
#pragma unroll
    for (int n = 0; n < DS; ++n) Hn[n] = 0.f;
    for (int s2 = 0; s2 < sg; ++s2) {
        long gi = (((long)b * NSEG + s2) * DI + d) * DS;
        float S = Sseg[((long)b * NSEG + s2) * DI + d];
        const f32x4* Gp = (const f32x4*)(Gseg + gi);
#pragma unroll
        for (int q = 0; q < 4; ++q) {
            f32x4 g4 = Gp[q];
#pragma unroll
            for (int j = 0; j < 4; ++j) {
                int n = q * 4 + j;
                Hn[n] = __expf(An_r[n] * S) * Hn[n] + g4[j];
            }
        }
    }
    const f32x4* Pp = (const f32x4*)(hpref + o);
#pragma unroll
    for (int q = 0; q < 4; ++q) {
        f32x4 p4 = Pp[q];
#pragma unroll
        for (int j = 0; j < 4; ++j) {
            int n = q * 4 + j;
            h[n] = __expf(An_r[n] * cs) * Hn[n] + p4[j];
        }
    }
    const float dcoef = Dp[d];
    __syncthreads();
#pragma unroll 4
    for (int s = 0; s < CLEN; ++s) {
        long bt = rowb + s;
        float xcv = bf2f(xcbf[bt * DI + d]);
        float dtv = bf2f(dt[bt * DI + d]);
        const f32x4* bp = (const f32x4*)&Bsh[s * 16];
        const f32x4* cp = (const f32x4*)&Csh[s * 16];
        float du = dtv * xcv;
        float yp[4] = {xcv * dcoef, 0.f, 0.f, 0.f};
#pragma unroll
        for (int q = 0; q < 4; ++q) {
            f32x4 b4 = bp[q], c4 = cp[q];
#pragma unroll
            for (int j = 0; j < 4; ++j) {
                int n = q * 4 + j;
                h[n] = __expf(An_r[n] * dtv) * h[n] + du * b4[j];
                yp[j] += h[n] * c4[j];
            }
        }
        float y = (yp[0] + yp[1]) + (yp[2] + yp[3]);
        float zv = bf2f(xz[bt * 3072 + DI + d]);
        y *= zv / (1.f + __expf(-zv));
        ybf[bt * DI + d] = f2bf(y);
    }
}

// ---------------- LayerNorm + residual (+ final store; zeroes Dbl for next layer) ----------------
__global__ __launch_bounds__(256) void k_ln(const float* __restrict__ prj,
                                            float* __restrict__ x,
                                            unsigned short* __restrict__ xbf,
                                            const float* __restrict__ lg,
                                            const float* __restrict__ lb,
                                            void* __restrict__ dout,
                                            float* __restrict__ dblz,
                                            int is_last, const int* __restrict__ flag) {
    __shared__ float red[8];
    const int row = blockIdx.x;
    const int tid = threadIdx.x;
    float v[3];
    float s = 0.f, s2 = 0.f;
#pragma unroll
    for (int j = 0; j < 3; ++j) {
        v[j] = prj[(long)row * DM + tid + j * 256];
        s += v[j];
        s2 += v[j] * v[j];
    }
    for (int off = 32; off; off >>= 1) {
        s  += __shfl_down(s, off, 64);
        s2 += __shfl_down(s2, off, 64);
    }
    if ((tid & 63) == 0) { red[tid >> 6] = s; red[4 + (tid >> 6)] = s2; }
    __syncthreads();
    float S  = red[0] + red[1] + red[2] + red[3];
    float S2 = red[4] + red[5] + red[6] + red[7];
    float mu = S * (1.f / DM);
    float var = S2 * (1.f / DM) - mu * mu;
    float rs = rsqrtf(var + 1e-5f);
    int bf = *flag;
#pragma unroll
    for (int j = 0; j < 3; ++j) {
        int e = tid + j * 256;
        long idx = (long)row * DM + e;
        float out = (v[j] - mu) * rs * lg[e] + lb[e] + x[idx];
        x[idx] = out;
        xbf[idx] = f2bf(out);
        if (is_last) {
            if (bf) ((unsigned short*)dout)[idx] = f2bf(out);
            else    ((float*)dout)[idx] = out;
        }
    }
    long gid = (long)row * 256 + tid;
    if (gid < 524288) dblz[gid] = 0.f;
}

// ---------------- host launcher ----------------
extern "C" void kernel_launch(void* const* d_in, const int* in_sizes, int n_in,
                              void* d_out, int out_size, void* d_ws, size_t ws_size,
                              hipStream_t stream) {
    char* ws = (char*)d_ws;
    const size_t O_FLAG = 0;
    const size_t O_WIN  = 256;
    const size_t O_WXP  = O_WIN  + 18874368;
    const size_t O_WDT  = O_WXP  + 1572864;
    const size_t O_WOUT = O_WDT  + 786432;
    const size_t O_PRM  = O_WOUT + 9437184;
    const size_t O_XBF  = O_PRM  + 589824;
    const size_t O_XF   = O_XBF  + 6291456;
    const size_t O_XZ   = O_XF   + 12582912;   // bf16 [4096,3072]; f32 Prj aliases
    const size_t O_XCBF = O_XZ   + 25165824;   // bf16 [4096,1536]
    const size_t O_DBL  = O_XCBF + 12582912;   // f32 [4096,128]
    const size_t O_DT   = O_DBL  + 2097152;    // bf16 [4096,1536]
    const size_t O_HCH  = O_DT   + 12582912;   // f32 [2,64,1536,16]
    const size_t O_SDT  = O_HCH  + 12582912;
    const size_t O_CUM  = O_SDT  + 786432;
    const size_t O_GSEG = O_CUM  + 786432;
    const size_t O_SSEG = O_GSEG + 1572864;
    const size_t O_YBF  = O_SSEG + 98304;

    int* flag = (int*)(ws + O_FLAG);
    unsigned short* Win  = (unsigned short*)(ws + O_WIN);
    unsigned short* Wxp  = (unsigned short*)(ws + O_WXP);
    unsigned short* Wdt  = (unsigned short*)(ws + O_WDT);
    unsigned short* Wout = (unsigned short*)(ws + O_WOUT);
    float* prm = (float*)(ws + O_PRM);
    unsigned short* Xbf = (unsigned short*)(ws + O_XBF);
    float* Xf  = (float*)(ws + O_XF);
    unsigned short* Xz = (unsigned short*)(ws + O_XZ);
    unsigned short* Xcbf = (unsigned short*)(ws + O_XCBF);
    float* Dbl = (float*)(ws + O_DBL);
    unsigned short* Dt = (unsigned short*)(ws + O_DT);
    float* Hch = (float*)(ws + O_HCH);
    float* Sdt = (float*)(ws + O_SDT);
    float* Cum = (float*)(ws + O_CUM);
    float* Gsg = (float*)(ws + O_GSEG);
    float* Ssg = (float*)(ws + O_SSEG);
    unsigned short* Ybf = (unsigned short*)(ws + O_YBF);
    float* Prj = (float*)(ws + O_XZ);   // alias: z consumed by scan3 before out_proj writes

    k_sniff<<<1, 256, 0, stream>>>((const unsigned short*)d_in[0], flag);
    k_prep<<<9352, 256, 0, stream>>>(d_in[0], d_in[1], d_in[9], d_in[4], d_in[5],
                                     d_in[6], d_in[7], d_in[8], d_in[2], d_in[3],
                                     d_in[10], d_in[11],
                                     Xbf, Xf, Win, Wout, Wxp, Wdt, prm, Dbl, flag);

    for (int l = 0; l < 4; ++l) {
        const unsigned short* winL  = Win  + (size_t)l * 3072 * 768;
        const unsigned short* wxpL  = Wxp  + (size_t)l * 128 * 1536;
        const unsigned short* wdtL  = Wdt  + (size_t)l * 1536 * 64;
        const unsigned short* woutL = Wout + (size_t)l * 768 * 1536;
        const float* cwL  = prm + OFF_CW  + (size_t)l * DI * 4;
        const float* cbL  = prm + OFF_CB  + (size_t)l * DI;
        const float* dtbL = prm + OFF_DTB + (size_t)l * DI;
        const float* anL  = prm + OFF_A   + (size_t)l * DI * DS;
        const float* dpL  = prm + OFF_DP  + (size_t)l * DI;
        const float* lgL  = prm + OFF_LG  + (size_t)l * DM;
        const float* lbL  = prm + OFF_LB  + (size_t)l * DM;

        k_gemm128<<<dim3(24, 32), 256, 0, stream>>>(Xbf, winL, Xz, NROWS, 2 * DI, DM);
        k_conv<<<dim3(24, 32), 256, 0, stream>>>(Xz, cwL, cbL, Xcbf);
        k_xproj<<<dim3(2, 64, 4), 256, 0, stream>>>(Xcbf, wxpL, Dbl);
        k_dtproj<<<dim3(24, 64), 256, 0, stream>>>(Dbl, wdtL, dtbL, Dt);
        k_scan1<<<BB * NCH * 6, 256, 0, stream>>>(Dt, Xcbf, Dbl, anL, Hch, Sdt);
        k_scan2a<<<1536, 256, 0, stream>>>(Hch, Sdt, anL, Cum, Gsg, Ssg);
        k_scan3<<<BB * NCH * 6, 256, 0, stream>>>(Dt, Xcbf, Xz, Dbl, anL, dpL,
                                                  Hch, Cum, Gsg, Ssg, Ybf);
        k_outproj<<<dim3(12, 64), 256, 0, stream>>>(Ybf, woutL, Prj);
        k_ln<<<4096, 256, 0, stream>>>(Prj, Xf, Xbf, lgL, lbL, d_out, Dbl,
                                       (l == 3) ? 1 : 0, flag);
    }
}